// Round 9
// baseline (710.513 us; speedup 1.0000x reference)
//
#include <hip/hip_runtime.h>
#include <hip/hip_cooperative_groups.h>
#include <math.h>

namespace cg = cooperative_groups;

#define Nn 15000
#define NP 15008   // padded node count (gru tiles of 16, no bounds checks)
#define Ee 30000
#define NB_E 118   // ceil(Ee/256)
#define EB 938     // k_edge4 blocks (3752 waves x 8 edges)

// ---- workspace layout (float offsets) ----
// zero region (memset each call):
#define OFF_AGG   0          // [NP*64]
#define OFF_DEG   960512     // [Nn]
#define ZERO_END  975520
// written-before-read region:
#define OFF_OUT   975520     // [NP*64]
#define OFF_DINV  1936032    // [Nn]
#define OFF_AT    1951040    // [65*4096] transposed: At[p][o*64+i]
#define OFF_BT    2217280    // [65*4096]
#define OFF_BP    2483520    // [64]
#define OFF_U     2483584    // [65*64]
#define OFF_V     2487744    // [65*64]
#define OFF_MC    2491904    // [1] int
#define OFF_PE    2491920    // [Ee] int
#define OFF_BH    2521920    // [NB_E*65] int
#define OFF_BC    2529592    // [NB_E*65] int
#define OFF_SS    2537264    // [Ee] int
#define OFF_SD    2567264    // [Ee] int
#define OFF_SA    2597264    // [Ee] float
#define OFF_SP    2627264    // [Ee] int
#define OFF_PK    2657264    // [7*4096] packed GRU weights
#define OFF_GMA   2685936    // [256]
#define OFF_GSA   2686192    // [256]
#define OFF_GRA   2686448    // [256*64]
#define OFF_GMB   2702832    // [256]
#define OFF_GSB   2703088    // [256]
#define OFF_GRB   2703344    // [256*64]
#define OFF_HS    2719728    // [64]  (fallback path only)
#define OFF_CS    2719792    // [64]
#define WS_FLOATS 2719856

__device__ __forceinline__ float sigf(float x) { return 1.0f / (1.0f + expf(-x)); }
__device__ __forceinline__ float bcast(float v, int l) {
    return __int_as_float(__builtin_amdgcn_readlane(__float_as_int(v), l));
}
__device__ __forceinline__ int bcasti(int v, int l) {
    return __builtin_amdgcn_readlane(v, l);
}

// zero-padded: nodes [Nn, NP) get h = 0
__global__ void k_lin0(const float* __restrict__ x, const float* __restrict__ w,
                       const float* __restrict__ b, float* __restrict__ out) {
    int idx = blockIdx.x * 256 + threadIdx.x;
    if (idx >= NP * 64) return;
    int n = idx >> 6, o = idx & 63;
    float v = 0.f;
    if (n < Nn)
        v = fmaxf(b[o] + x[n*3+0]*w[o*3+0] + x[n*3+1]*w[o*3+1] + x[n*3+2]*w[o*3+2], 0.f);
    out[idx] = v;
}

// he[e,k] = relu(a*w1[k]+b1[k]) piecewise-linear in scalar a: <=64 breakpoints.
__global__ void k_patterns(const float* __restrict__ e1w, const float* __restrict__ e1b,
                           float* __restrict__ bp, float* __restrict__ u,
                           float* __restrict__ v, int* __restrict__ mc) {
    __shared__ float t[64]; __shared__ int valid[64]; __shared__ float sbp[65]; __shared__ int cnt;
    int k = threadIdx.x;
    float w1 = e1w[k], b1 = e1b[k];
    float tv = 0.f; int va = 0;
    if (w1 != 0.f) { tv = -b1 / w1; va = (tv > 0.f && tv < 1.f) ? 1 : 0; }
    t[k] = tv; valid[k] = va;
    __syncthreads();
    if (va) {
        int rank = 0;
        for (int kk = 0; kk < 64; ++kk)
            if (valid[kk] && (t[kk] < tv || (t[kk] == tv && kk < k))) rank++;
        sbp[rank] = tv;
    }
    if (k == 0) { int c = 0; for (int kk = 0; kk < 64; ++kk) c += valid[kk]; cnt = c; *mc = c; }
    __syncthreads();
    int m = cnt;
    if (k < m) bp[k] = sbp[k];
    for (int j = 0; j <= m; ++j) {
        float lo = (j == 0) ? 0.f : sbp[j-1];
        float hi = (j == m) ? 1.f : sbp[j];
        float c = 0.5f * (lo + hi);
        int msk = (c * w1 + b1) > 0.f;
        u[j*64 + k] = msk ? w1 : 0.f;
        v[j*64 + k] = msk ? b1 : 0.f;
    }
}

// parallel A/B build: grid 65x16
__global__ void k_AB2(const float* __restrict__ e2w, const float* __restrict__ e2b,
                      const float* __restrict__ u, const float* __restrict__ v,
                      const int* __restrict__ mc, float* __restrict__ At, float* __restrict__ Bt) {
    int j = blockIdx.x >> 4;
    if (j > *mc) return;
    int qc = blockIdx.x & 15;
    __shared__ float su[64], sv[64];
    if (threadIdx.x < 64) { su[threadIdx.x] = u[j*64+threadIdx.x]; sv[threadIdx.x] = v[j*64+threadIdx.x]; }
    __syncthreads();
    int q = qc*256 + threadIdx.x;
    int i = q >> 6, o = q & 63;
    const float* row = e2w + q*64;
    float a = 0.f, b = 0.f;
    #pragma unroll 8
    for (int k = 0; k < 64; ++k) { float w = row[k]; a = fmaf(su[k], w, a); b = fmaf(sv[k], w, b); }
    At[j*4096 + o*64 + i] = a;
    Bt[j*4096 + o*64 + i] = b + e2b[q];
}

__global__ void k_eprep2(const int* __restrict__ ei, const float* __restrict__ ea,
                         const float* __restrict__ bp, const int* __restrict__ mc,
                         float* __restrict__ deg, int* __restrict__ pe, int* __restrict__ bh) {
    __shared__ int lh[65];
    int tid = threadIdx.x;
    if (tid < 65) lh[tid] = 0;
    __syncthreads();
    int e = blockIdx.x * 256 + tid;
    if (e < Ee) {
        atomicAdd(&deg[ei[Ee + e]], 1.0f);
        float a = ea[e];
        int m = *mc, p = 0;
        for (int j = 0; j < m; ++j) p += (bp[j] <= a) ? 1 : 0;
        pe[e] = p;
        atomicAdd(&lh[p], 1);
    }
    __syncthreads();
    if (tid < 65) bh[blockIdx.x*65 + tid] = lh[tid];
}

__global__ void k_scan2(const float* __restrict__ deg, float* __restrict__ dinv,
                        const int* __restrict__ bh, int* __restrict__ bc) {
    int tid = threadIdx.x;
    if (blockIdx.x < 59) {
        int n = blockIdx.x * 256 + tid;
        if (n < Nn) dinv[n] = 1.0f / fmaxf(deg[n], 1.0f);
        return;
    }
    __shared__ int stot[65]; __shared__ int sbase[65];
    if (tid < 65) {
        int t = 0;
        for (int b = 0; b < NB_E; ++b) t += bh[b*65 + tid];
        stot[tid] = t;
    }
    __syncthreads();
    if (tid == 0) {
        int run = 0;
        for (int j = 0; j < 65; ++j) { sbase[j] = run; run += stot[j]; }
    }
    __syncthreads();
    if (tid < 65) {
        int run = sbase[tid];
        for (int b = 0; b < NB_E; ++b) { bc[b*65 + tid] = run; run += bh[b*65 + tid]; }
    }
}

__global__ void k_scatter2(const int* __restrict__ ei, const float* __restrict__ ea,
                           const int* __restrict__ pe, const int* __restrict__ bc,
                           int* __restrict__ sS, int* __restrict__ sD,
                           float* __restrict__ sA, int* __restrict__ sP) {
    __shared__ int cur[65];
    int tid = threadIdx.x;
    if (tid < 65) cur[tid] = bc[blockIdx.x*65 + tid];
    __syncthreads();
    int e = blockIdx.x * 256 + tid;
    if (e >= Ee) return;
    int p = pe[e];
    int pos = atomicAdd(&cur[p], 1);
    sS[pos] = ei[e]; sD[pos] = ei[Ee + e]; sA[pos] = ea[e]; sP[pos] = p;
}

// pk[g*4096 + i4*256 + lane*4 + k] = Wg[i4*4+k][lane]
// g: 0=root; 1..3 whh gates r,z,n; 4..6 wih gates r,z,n
__global__ void k_wt2(const float* __restrict__ rootw, const float* __restrict__ whh,
                      const float* __restrict__ wih, float* __restrict__ pk) {
    int idx = blockIdx.x * 256 + threadIdx.x;
    if (idx >= 7*4096) return;
    int g = idx >> 12;
    int t = idx & 4095;
    int q4 = t >> 2, k = t & 3;
    int lane = q4 & 63;
    int i4 = q4 >> 6;
    int i = i4*4 + k;
    float v;
    if (g == 0)      v = rootw[i*64 + lane];
    else if (g < 4)  v = whh[((g-1)*64 + lane)*64 + i];
    else             v = wih[((g-4)*64 + lane)*64 + i];
    pk[idx] = v;
}

// pattern-sorted edges; chunk metadata lane-parallel; h-row pipelined one ahead.
__global__ __launch_bounds__(256) void k_edge4(
        const int* __restrict__ sS, const int* __restrict__ sD,
        const float* __restrict__ sA, const int* __restrict__ sP,
        const float* __restrict__ out, const float* __restrict__ At,
        const float* __restrict__ Bt, const float* __restrict__ dinv,
        float* __restrict__ agg) {
    int tid = threadIdx.x, lane = tid & 63;
    int wid = (blockIdx.x * 256 + tid) >> 6;
    const int CH = 8;
    int e0 = wid * CH;
    if (e0 >= Ee) return;
    int e1 = e0 + CH; if (e1 > Ee) e1 = Ee;
    int cnt = e1 - e0;

    int eidx = e0 + lane;
    int msrc = 0, mdst = 0, mp = 0; float ma = 0.f, mdv = 0.f;
    if (lane < cnt) {
        msrc = sS[eidx]; mdst = sD[eidx]; ma = sA[eidx]; mp = sP[eidx];
        mdv = dinv[mdst];
    }

    float Ar[64], Br[64];
    int curp = -1;
    float hv_next = out[bcasti(msrc, 0)*64 + lane];
    for (int j = 0; j < cnt; ++j) {
        float hv = hv_next;
        if (j+1 < cnt) hv_next = out[bcasti(msrc, j+1)*64 + lane];
        int p = bcasti(mp, j);
        if (p != curp) {
            curp = p;
            const float4* Ap4 = (const float4*)(At + p*4096 + lane*64);
            const float4* Bp4 = (const float4*)(Bt + p*4096 + lane*64);
            #pragma unroll
            for (int q = 0; q < 16; ++q) {
                float4 av = Ap4[q], bv = Bp4[q];
                Ar[q*4+0]=av.x; Ar[q*4+1]=av.y; Ar[q*4+2]=av.z; Ar[q*4+3]=av.w;
                Br[q*4+0]=bv.x; Br[q*4+1]=bv.y; Br[q*4+2]=bv.z; Br[q*4+3]=bv.w;
            }
        }
        float a = bcast(ma, j);
        float acc0 = 0.f, acc1 = 0.f;
        #pragma unroll
        for (int i = 0; i < 64; i += 2) {
            float h0 = bcast(hv, i);
            float h1 = bcast(hv, i+1);
            acc0 = fmaf(h0, fmaf(a, Ar[i],   Br[i]),   acc0);
            acc1 = fmaf(h1, fmaf(a, Ar[i+1], Br[i+1]), acc1);
        }
        float acc = (acc0 + acc1) * bcast(mdv, j);
        atomicAdd(&agg[bcasti(mdst, j)*64 + lane], acc);
    }
}

// fused NNConv-root + GRU: 4 waves x 2 gates (readlane amortized over 2 FMAs),
// 16-node tile (NP padded -> no bounds checks), weights VGPR-resident
// (launch_bounds(256,2) -> 256-VGPR cap).
__global__ __launch_bounds__(256, 2) void k_gru8(
        float* __restrict__ out, float* __restrict__ agg,
        const float* __restrict__ pk, const float* __restrict__ convb,
        const float* __restrict__ gbih, const float* __restrict__ gbhh) {
    __shared__ float mL[1024];   // m
    __shared__ float gA[1024];   // gh_r -> r
    __shared__ float gB[1024];   // gh_z -> z
    __shared__ float gC[1024];   // gh_n raw
    __shared__ float gD[1024];   // gi_n + bih_n
    int tid = threadIdx.x, lane = tid & 63, w = tid >> 6;
    int pr = w >> 1, hf = w & 1;
    int n0 = blockIdx.x * 16;
    const float4* pk4 = (const float4*)pk;

    float4 wa[16], wb[16];
    {
        int g0 = pr*2, g1 = pr*2 + 1;
        #pragma unroll
        for (int i4 = 0; i4 < 16; ++i4) {
            wa[i4] = pk4[(g0*16 + i4)*64 + lane];
            wb[i4] = pk4[(g1*16 + i4)*64 + lane];
        }
    }
    float cbv = convb[lane];
    int nb0 = n0 + hf*8;

    #pragma unroll
    for (int nb = 0; nb < 8; nb += 4) {
        int n = nb0 + nb;
        float hv0 = out[(n+0)*64 + lane];
        float hv1 = out[(n+1)*64 + lane];
        float hv2 = out[(n+2)*64 + lane];
        float hv3 = out[(n+3)*64 + lane];
        float a0=0.f,a1=0.f,a2=0.f,a3=0.f, b0=0.f,b1=0.f,b2=0.f,b3=0.f;
        #pragma unroll
        for (int i4 = 0; i4 < 16; ++i4) {
            float4 va = wa[i4], vb = wb[i4];
            float h;
            h = bcast(hv0, i4*4+0); a0 = fmaf(h, va.x, a0); b0 = fmaf(h, vb.x, b0);
            h = bcast(hv1, i4*4+0); a1 = fmaf(h, va.x, a1); b1 = fmaf(h, vb.x, b1);
            h = bcast(hv2, i4*4+0); a2 = fmaf(h, va.x, a2); b2 = fmaf(h, vb.x, b2);
            h = bcast(hv3, i4*4+0); a3 = fmaf(h, va.x, a3); b3 = fmaf(h, vb.x, b3);
            h = bcast(hv0, i4*4+1); a0 = fmaf(h, va.y, a0); b0 = fmaf(h, vb.y, b0);
            h = bcast(hv1, i4*4+1); a1 = fmaf(h, va.y, a1); b1 = fmaf(h, vb.y, b1);
            h = bcast(hv2, i4*4+1); a2 = fmaf(h, va.y, a2); b2 = fmaf(h, vb.y, b2);
            h = bcast(hv3, i4*4+1); a3 = fmaf(h, va.y, a3); b3 = fmaf(h, vb.y, b3);
            h = bcast(hv0, i4*4+2); a0 = fmaf(h, va.z, a0); b0 = fmaf(h, vb.z, b0);
            h = bcast(hv1, i4*4+2); a1 = fmaf(h, va.z, a1); b1 = fmaf(h, vb.z, b1);
            h = bcast(hv2, i4*4+2); a2 = fmaf(h, va.z, a2); b2 = fmaf(h, vb.z, b2);
            h = bcast(hv3, i4*4+2); a3 = fmaf(h, va.z, a3); b3 = fmaf(h, vb.z, b3);
            h = bcast(hv0, i4*4+3); a0 = fmaf(h, va.w, a0); b0 = fmaf(h, vb.w, b0);
            h = bcast(hv1, i4*4+3); a1 = fmaf(h, va.w, a1); b1 = fmaf(h, vb.w, b1);
            h = bcast(hv2, i4*4+3); a2 = fmaf(h, va.w, a2); b2 = fmaf(h, vb.w, b2);
            h = bcast(hv3, i4*4+3); a3 = fmaf(h, va.w, a3); b3 = fmaf(h, vb.w, b3);
        }
        int ln = n - n0;
        float fa[4] = {a0,a1,a2,a3}, fb[4] = {b0,b1,b2,b3};
        if (pr == 0) {
            #pragma unroll
            for (int k2 = 0; k2 < 4; ++k2) {
                int gi = (n+k2)*64 + lane;
                float av = agg[gi]; agg[gi] = 0.f;
                mL[(ln+k2)*64 + lane] = fmaxf(fa[k2] + av + cbv, 0.f);
                gA[(ln+k2)*64 + lane] = fb[k2];
            }
        } else {
            #pragma unroll
            for (int k2 = 0; k2 < 4; ++k2) {
                gB[(ln+k2)*64 + lane] = fa[k2];
                gC[(ln+k2)*64 + lane] = fb[k2];
            }
        }
    }
    __syncthreads();

    // ---- phase B ----
    if (pr == 0) {   // gi_r, gi_z
        #pragma unroll
        for (int i4 = 0; i4 < 16; ++i4) {
            wa[i4] = pk4[(4*16 + i4)*64 + lane];
            wb[i4] = pk4[(5*16 + i4)*64 + lane];
        }
        float br = gbih[lane]      + gbhh[lane];
        float bz = gbih[64+lane]   + gbhh[64+lane];
        #pragma unroll
        for (int nb = 0; nb < 8; nb += 4) {
            int ln = hf*8 + nb;
            float mv0 = mL[(ln+0)*64 + lane];
            float mv1 = mL[(ln+1)*64 + lane];
            float mv2 = mL[(ln+2)*64 + lane];
            float mv3 = mL[(ln+3)*64 + lane];
            float a0=0.f,a1=0.f,a2=0.f,a3=0.f, b0=0.f,b1=0.f,b2=0.f,b3=0.f;
            #pragma unroll
            for (int i4 = 0; i4 < 16; ++i4) {
                float4 va = wa[i4], vb = wb[i4];
                float h;
                h = bcast(mv0, i4*4+0); a0 = fmaf(h, va.x, a0); b0 = fmaf(h, vb.x, b0);
                h = bcast(mv1, i4*4+0); a1 = fmaf(h, va.x, a1); b1 = fmaf(h, vb.x, b1);
                h = bcast(mv2, i4*4+0); a2 = fmaf(h, va.x, a2); b2 = fmaf(h, vb.x, b2);
                h = bcast(mv3, i4*4+0); a3 = fmaf(h, va.x, a3); b3 = fmaf(h, vb.x, b3);
                h = bcast(mv0, i4*4+1); a0 = fmaf(h, va.y, a0); b0 = fmaf(h, vb.y, b0);
                h = bcast(mv1, i4*4+1); a1 = fmaf(h, va.y, a1); b1 = fmaf(h, vb.y, b1);
                h = bcast(mv2, i4*4+1); a2 = fmaf(h, va.y, a2); b2 = fmaf(h, vb.y, b2);
                h = bcast(mv3, i4*4+1); a3 = fmaf(h, va.y, a3); b3 = fmaf(h, vb.y, b3);
                h = bcast(mv0, i4*4+2); a0 = fmaf(h, va.z, a0); b0 = fmaf(h, vb.z, b0);
                h = bcast(mv1, i4*4+2); a1 = fmaf(h, va.z, a1); b1 = fmaf(h, vb.z, b1);
                h = bcast(mv2, i4*4+2); a2 = fmaf(h, va.z, a2); b2 = fmaf(h, vb.z, b2);
                h = bcast(mv3, i4*4+2); a3 = fmaf(h, va.z, a3); b3 = fmaf(h, vb.z, b3);
                h = bcast(mv0, i4*4+3); a0 = fmaf(h, va.w, a0); b0 = fmaf(h, vb.w, b0);
                h = bcast(mv1, i4*4+3); a1 = fmaf(h, va.w, a1); b1 = fmaf(h, vb.w, b1);
                h = bcast(mv2, i4*4+3); a2 = fmaf(h, va.w, a2); b2 = fmaf(h, vb.w, b2);
                h = bcast(mv3, i4*4+3); a3 = fmaf(h, va.w, a3); b3 = fmaf(h, vb.w, b3);
            }
            float fa[4] = {a0,a1,a2,a3}, fb[4] = {b0,b1,b2,b3};
            #pragma unroll
            for (int k2 = 0; k2 < 4; ++k2) {
                int r4 = (ln+k2)*64 + lane;
                gA[r4] = sigf(fa[k2] + gA[r4] + br);
                gB[r4] = sigf(fb[k2] + gB[r4] + bz);
            }
        }
    } else {        // gi_n
        #pragma unroll
        for (int i4 = 0; i4 < 16; ++i4) wa[i4] = pk4[(6*16 + i4)*64 + lane];
        float bn = gbih[128 + lane];
        #pragma unroll
        for (int nb = 0; nb < 8; nb += 4) {
            int ln = hf*8 + nb;
            float mv0 = mL[(ln+0)*64 + lane];
            float mv1 = mL[(ln+1)*64 + lane];
            float mv2 = mL[(ln+2)*64 + lane];
            float mv3 = mL[(ln+3)*64 + lane];
            float a0=0.f,a1=0.f,a2=0.f,a3=0.f;
            #pragma unroll
            for (int i4 = 0; i4 < 16; ++i4) {
                float4 va = wa[i4];
                float h;
                h = bcast(mv0, i4*4+0); a0 = fmaf(h, va.x, a0);
                h = bcast(mv1, i4*4+0); a1 = fmaf(h, va.x, a1);
                h = bcast(mv2, i4*4+0); a2 = fmaf(h, va.x, a2);
                h = bcast(mv3, i4*4+0); a3 = fmaf(h, va.x, a3);
                h = bcast(mv0, i4*4+1); a0 = fmaf(h, va.y, a0);
                h = bcast(mv1, i4*4+1); a1 = fmaf(h, va.y, a1);
                h = bcast(mv2, i4*4+1); a2 = fmaf(h, va.y, a2);
                h = bcast(mv3, i4*4+1); a3 = fmaf(h, va.y, a3);
                h = bcast(mv0, i4*4+2); a0 = fmaf(h, va.z, a0);
                h = bcast(mv1, i4*4+2); a1 = fmaf(h, va.z, a1);
                h = bcast(mv2, i4*4+2); a2 = fmaf(h, va.z, a2);
                h = bcast(mv3, i4*4+2); a3 = fmaf(h, va.z, a3);
                h = bcast(mv0, i4*4+3); a0 = fmaf(h, va.w, a0);
                h = bcast(mv1, i4*4+3); a1 = fmaf(h, va.w, a1);
                h = bcast(mv2, i4*4+3); a2 = fmaf(h, va.w, a2);
                h = bcast(mv3, i4*4+3); a3 = fmaf(h, va.w, a3);
            }
            float fa[4] = {a0,a1,a2,a3};
            #pragma unroll
            for (int k2 = 0; k2 < 4; ++k2)
                gD[(ln+k2)*64 + lane] = fa[k2] + bn;
        }
    }
    __syncthreads();

    // ---- combine ----
    float bhn = gbhh[128 + lane];
    #pragma unroll
    for (int p = 0; p < 4; ++p) {
        int ln = p*4 + w;
        int r4 = ln*64 + lane;
        int gi = (n0 + ln)*64 + lane;
        float r = gA[r4], z = gB[r4];
        float nn = tanhf(fmaf(r, gC[r4] + bhn, gD[r4]));
        float h = out[gi];
        out[gi] = (1.f - z)*nn + z*h;
    }
}

// ---------- Set2Set: all 6 iterations + final, one cooperative kernel ----------
__global__ __launch_bounds__(512) void k_s2s_all(
        const float* __restrict__ swih, const float* __restrict__ swhh,
        const float* __restrict__ sbih, const float* __restrict__ sbhh,
        const float* __restrict__ mwih, const float* __restrict__ mbih,
        const float* __restrict__ mbhh, const float* __restrict__ out,
        float* __restrict__ gmA, float* __restrict__ gsA, float* __restrict__ grA,
        float* __restrict__ gmB, float* __restrict__ gsB, float* __restrict__ grB,
        const float* __restrict__ l1w, const float* __restrict__ l1b,
        const float* __restrict__ l3w, const float* __restrict__ l3b,
        float* __restrict__ dout) {
    cg::grid_group gridg = cg::this_grid();
    __shared__ float red[512], srv[64], sg[256];
    __shared__ float sm_m[8], sm_z[8], sm_r[8][64];
    __shared__ float s_hs[64], s_cs[64], shx[64], so[64];
    int tid = threadIdx.x, lane = tid & 63, w = tid >> 6;
    if (tid < 64) { s_hs[tid] = 0.f; s_cs[tid] = 0.f; srv[tid] = 0.f; }
    __syncthreads();

    for (int it = 0; it < 6; ++it) {
        if (it > 0) {
            const float* gmax_rd = (it & 1) ? gmA : gmB;
            const float* gsum_rd = (it & 1) ? gsA : gsB;
            const float* gr_rd   = (it & 1) ? grA : grB;
            float gm = (tid < 256) ? gmax_rd[tid] : -3.4e38f;
            red[tid] = gm; __syncthreads();
            for (int s = 256; s > 0; s >>= 1) { if (tid < s) red[tid] = fmaxf(red[tid], red[tid+s]); __syncthreads(); }
            float M = red[0]; __syncthreads();
            red[tid] = (tid < 256) ? gsum_rd[tid] * expf(gm - M) : 0.f; __syncthreads();
            for (int s = 256; s > 0; s >>= 1) { if (tid < s) red[tid] += red[tid+s]; __syncthreads(); }
            float Z = red[0]; __syncthreads();
            float racc = 0.f;
            for (int b = w; b < 256; b += 8) racc = fmaf(gr_rd[b*64 + lane], expf(gmax_rd[b] - M), racc);
            red[tid] = racc; __syncthreads();
            if (w == 0) {
                float s = 0.f;
                #pragma unroll
                for (int k = 0; k < 8; ++k) s += red[k*64 + lane];
                srv[lane] = s / Z;
            }
            __syncthreads();
        }
        if (tid < 256) {
            const float* wi = swih + tid*128;
            const float* wh = swhh + tid*64;
            float g = sbih[tid] + sbhh[tid];
            #pragma unroll 8
            for (int i = 0; i < 64; ++i) g += s_hs[i]*(wi[i] + wh[i]) + srv[i]*wi[64+i];
            sg[tid] = g;
        }
        __syncthreads();
        if (tid < 64) {
            float ii = sigf(sg[tid]), ff = sigf(sg[64+tid]);
            float gg = tanhf(sg[128+tid]), oo = sigf(sg[192+tid]);
            float c2 = ff*s_cs[tid] + ii*gg;
            s_cs[tid] = c2;
            s_hs[tid] = oo*tanhf(c2);
        }
        __syncthreads();

        float hsv = s_hs[lane];
        float m = -3.4e38f, Z2 = 0.f, racc2 = 0.f;
        for (int n = blockIdx.x*8 + w; n < Nn; n += 2048) {
            float ov = out[n*64 + lane];
            float p = ov * hsv;
            #pragma unroll
            for (int off = 32; off > 0; off >>= 1) p += __shfl_xor(p, off, 64);
            float mn = fmaxf(m, p);
            float sc = expf(m - mn);
            float t  = expf(p - mn);
            Z2 = fmaf(Z2, sc, t);
            racc2 = fmaf(racc2, sc, t*ov);
            m = mn;
        }
        if (lane == 0) { sm_m[w] = m; sm_z[w] = Z2; }
        sm_r[w][lane] = racc2;
        __syncthreads();
        if (w == 0) {
            float* gmax_wr = (it & 1) ? gmB : gmA;
            float* gsum_wr = (it & 1) ? gsB : gsA;
            float* gr_wr   = (it & 1) ? grB : grA;
            float M = sm_m[0];
            #pragma unroll
            for (int j = 1; j < 8; ++j) M = fmaxf(M, sm_m[j]);
            float Zb = 0.f, rb = 0.f;
            #pragma unroll
            for (int j = 0; j < 8; ++j) {
                float e = expf(sm_m[j] - M);
                Zb = fmaf(sm_z[j], e, Zb);
                rb = fmaf(sm_r[j][lane], e, rb);
            }
            gr_wr[blockIdx.x*64 + lane] = rb;
            if (lane == 0) { gmax_wr[blockIdx.x] = M; gsum_wr[blockIdx.x] = Zb; }
        }
        gridg.sync();
    }

    // final (it=5 wrote B buffers): block 0 only
    if (blockIdx.x == 0) {
        float gm = (tid < 256) ? gmB[tid] : -3.4e38f;
        red[tid] = gm; __syncthreads();
        for (int s = 256; s > 0; s >>= 1) { if (tid < s) red[tid] = fmaxf(red[tid], red[tid+s]); __syncthreads(); }
        float M = red[0]; __syncthreads();
        red[tid] = (tid < 256) ? gsB[tid] * expf(gm - M) : 0.f; __syncthreads();
        for (int s = 256; s > 0; s >>= 1) { if (tid < s) red[tid] += red[tid+s]; __syncthreads(); }
        float Z = red[0]; __syncthreads();
        float racc = 0.f;
        for (int b = w; b < 256; b += 8) racc = fmaf(grB[b*64 + lane], expf(gmB[b] - M), racc);
        red[tid] = racc; __syncthreads();
        if (w == 0) {
            float s = 0.f;
            #pragma unroll
            for (int k = 0; k < 8; ++k) s += red[k*64 + lane];
            srv[lane] = s / Z;
        }
        __syncthreads();
        if (tid < 256) {
            const float* wi = mwih + tid*128;
            float g = mbih[tid] + mbhh[tid];
            #pragma unroll 8
            for (int i = 0; i < 64; ++i) g += s_hs[i]*wi[i] + srv[i]*wi[64+i];
            sg[tid] = g;
        }
        __syncthreads();
        if (tid < 64) {
            float ii = sigf(sg[tid]);
            float gg = tanhf(sg[128+tid]);
            float oo = sigf(sg[192+tid]);
            float c2 = ii * gg;
            float hx = oo * tanhf(c2);
            shx[tid] = hx;
            dout[1 + tid] = hx;
            dout[65 + tid] = c2;
        }
        __syncthreads();
        if (tid < 64) {
            float a = l1b[tid];
            const float* wr = l1w + tid*64;
            #pragma unroll 8
            for (int i = 0; i < 64; ++i) a = fmaf(shx[i], wr[i], a);
            so[tid] = fmaxf(a, 0.f);
        }
        __syncthreads();
        if (tid == 0) {
            float v = l3b[0];
            for (int i = 0; i < 64; ++i) v = fmaf(so[i], l3w[i], v);
            dout[0] = v;
        }
    }
}

// ---------- fallback (non-cooperative) Set2Set kernels ----------
__global__ __launch_bounds__(512) void k_s2s(
        const float* __restrict__ wih, const float* __restrict__ whh,
        const float* __restrict__ bih, const float* __restrict__ bhh,
        float* __restrict__ hs, float* __restrict__ cs,
        const float* __restrict__ out,
        const float* __restrict__ gmax_rd, const float* __restrict__ gsum_rd,
        const float* __restrict__ gr_rd,
        float* __restrict__ gmax_wr, float* __restrict__ gsum_wr,
        float* __restrict__ gr_wr, int it) {
    __shared__ float red[512], shs[64], scs[64], srv[64], sg[256];
    __shared__ float sm_m[8], sm_z[8], sm_r[8][64];
    int tid = threadIdx.x, lane = tid & 63, w = tid >> 6;
    if (it == 0) {
        if (tid < 64) { shs[tid] = 0.f; scs[tid] = 0.f; srv[tid] = 0.f; }
    } else {
        float gm = (tid < 256) ? gmax_rd[tid] : -3.4e38f;
        red[tid] = gm; __syncthreads();
        for (int s = 256; s > 0; s >>= 1) { if (tid < s) red[tid] = fmaxf(red[tid], red[tid+s]); __syncthreads(); }
        float M = red[0]; __syncthreads();
        red[tid] = (tid < 256) ? gsum_rd[tid] * expf(gm - M) : 0.f; __syncthreads();
        for (int s = 256; s > 0; s >>= 1) { if (tid < s) red[tid] += red[tid+s]; __syncthreads(); }
        float Z = red[0]; __syncthreads();
        float racc = 0.f;
        for (int b = w; b < 256; b += 8) racc = fmaf(gr_rd[b*64 + lane], expf(gmax_rd[b] - M), racc);
        red[tid] = racc; __syncthreads();
        if (w == 0) {
            float s = 0.f;
            #pragma unroll
            for (int k = 0; k < 8; ++k) s += red[k*64 + lane];
            srv[lane] = s / Z;
        }
        if (tid < 64) { shs[tid] = hs[tid]; scs[tid] = cs[tid]; }
    }
    __syncthreads();
    if (tid < 256) {
        const float* wi = wih + tid*128;
        const float* wh = whh + tid*64;
        float g = bih[tid] + bhh[tid];
        #pragma unroll 8
        for (int i = 0; i < 64; ++i) g += shs[i]*(wi[i] + wh[i]) + srv[i]*wi[64+i];
        sg[tid] = g;
    }
    __syncthreads();
    if (tid < 64) {
        float ii = sigf(sg[tid]), ff = sigf(sg[64+tid]);
        float gg = tanhf(sg[128+tid]), oo = sigf(sg[192+tid]);
        float c2 = ff*scs[tid] + ii*gg;
        float hn = oo*tanhf(c2);
        shs[tid] = hn;
        if (blockIdx.x == 0) { hs[tid] = hn; cs[tid] = c2; }
    }
    __syncthreads();
    float hsv = shs[lane];
    float m = -3.4e38f, Z2 = 0.f, racc2 = 0.f;
    for (int n = blockIdx.x*8 + w; n < Nn; n += 2048) {
        float ov = out[n*64 + lane];
        float p = ov * hsv;
        #pragma unroll
        for (int off = 32; off > 0; off >>= 1) p += __shfl_xor(p, off, 64);
        float mn = fmaxf(m, p);
        float sc = expf(m - mn);
        float t  = expf(p - mn);
        Z2 = fmaf(Z2, sc, t);
        racc2 = fmaf(racc2, sc, t*ov);
        m = mn;
    }
    if (lane == 0) { sm_m[w] = m; sm_z[w] = Z2; }
    sm_r[w][lane] = racc2;
    __syncthreads();
    if (w == 0) {
        float M = sm_m[0];
        #pragma unroll
        for (int j = 1; j < 8; ++j) M = fmaxf(M, sm_m[j]);
        float Zb = 0.f, rb = 0.f;
        #pragma unroll
        for (int j = 0; j < 8; ++j) {
            float e = expf(sm_m[j] - M);
            Zb = fmaf(sm_z[j], e, Zb);
            rb = fmaf(sm_r[j][lane], e, rb);
        }
        gr_wr[blockIdx.x*64 + lane] = rb;
        if (lane == 0) { gmax_wr[blockIdx.x] = M; gsum_wr[blockIdx.x] = Zb; }
    }
}

__global__ __launch_bounds__(256) void k_final2(const float* __restrict__ mwih,
        const float* __restrict__ mbih, const float* __restrict__ mbhh,
        const float* __restrict__ hs,
        const float* __restrict__ gmax, const float* __restrict__ gsum,
        const float* __restrict__ gr,
        const float* __restrict__ l1w, const float* __restrict__ l1b,
        const float* __restrict__ l3w, const float* __restrict__ l3b,
        float* __restrict__ dout) {
    __shared__ float red[256], shs[64], srv[64], sg[256], shx[64], so[64];
    int tid = threadIdx.x, lane = tid & 63, w = tid >> 6;
    {
        float gm = gmax[tid];
        red[tid] = gm; __syncthreads();
        for (int s = 128; s > 0; s >>= 1) { if (tid < s) red[tid] = fmaxf(red[tid], red[tid+s]); __syncthreads(); }
        float M = red[0]; __syncthreads();
        red[tid] = gsum[tid] * expf(gm - M); __syncthreads();
        for (int s = 128; s > 0; s >>= 1) { if (tid < s) red[tid] += red[tid+s]; __syncthreads(); }
        float Z = red[0]; __syncthreads();
        float racc = 0.f;
        for (int b = w; b < 256; b += 4) racc = fmaf(gr[b*64 + lane], expf(gmax[b] - M), racc);
        red[tid] = racc; __syncthreads();
        if (w == 0) srv[lane] = (red[lane] + red[64+lane] + red[128+lane] + red[192+lane]) / Z;
        if (tid < 64) shs[tid] = hs[tid];
    }
    __syncthreads();
    const float* wi = mwih + tid*128;
    float g = mbih[tid] + mbhh[tid];
    #pragma unroll 8
    for (int i = 0; i < 64; ++i) g += shs[i]*wi[i] + srv[i]*wi[64+i];
    sg[tid] = g; __syncthreads();
    if (tid < 64) {
        float ii = sigf(sg[tid]);
        float gg = tanhf(sg[128+tid]);
        float oo = sigf(sg[192+tid]);
        float c2 = ii * gg;
        float hx = oo * tanhf(c2);
        shx[tid] = hx;
        dout[1 + tid] = hx;
        dout[65 + tid] = c2;
    }
    __syncthreads();
    if (tid < 64) {
        float a = l1b[tid];
        const float* wr = l1w + tid*64;
        #pragma unroll 8
        for (int i = 0; i < 64; ++i) a = fmaf(shx[i], wr[i], a);
        so[tid] = fmaxf(a, 0.f);
    }
    __syncthreads();
    if (tid == 0) {
        float v = l3b[0];
        for (int i = 0; i < 64; ++i) v = fmaf(so[i], l3w[i], v);
        dout[0] = v;
    }
}

extern "C" void kernel_launch(void* const* d_in, const int* in_sizes, int n_in,
                              void* d_out, int out_size, void* d_ws, size_t ws_size,
                              hipStream_t stream) {
    const float* x    = (const float*)d_in[0];
    const int*   ei   = (const int*)  d_in[1];
    const float* ea   = (const float*)d_in[2];
    const float* l0w  = (const float*)d_in[3];
    const float* l0b  = (const float*)d_in[4];
    const float* e1w  = (const float*)d_in[5];
    const float* e1b  = (const float*)d_in[6];
    const float* e2w  = (const float*)d_in[7];
    const float* e2b  = (const float*)d_in[8];
    const float* rootw= (const float*)d_in[9];
    const float* convb= (const float*)d_in[10];
    const float* gwih = (const float*)d_in[11];
    const float* gwhh = (const float*)d_in[12];
    const float* gbih = (const float*)d_in[13];
    const float* gbhh = (const float*)d_in[14];
    const float* swih = (const float*)d_in[15];
    const float* swhh = (const float*)d_in[16];
    const float* sbih = (const float*)d_in[17];
    const float* sbhh = (const float*)d_in[18];
    const float* mwih = (const float*)d_in[19];
    const float* mbih = (const float*)d_in[21];
    const float* mbhh = (const float*)d_in[22];
    const float* l1w  = (const float*)d_in[23];
    const float* l1b  = (const float*)d_in[24];
    const float* l3w  = (const float*)d_in[25];
    const float* l3b  = (const float*)d_in[26];

    float* ws   = (float*)d_ws;
    float* dout = (float*)d_out;
    if (ws_size < (size_t)WS_FLOATS * sizeof(float)) return;

    float* agg  = ws + OFF_AGG;
    float* deg  = ws + OFF_DEG;
    float* out  = ws + OFF_OUT;
    float* dinv = ws + OFF_DINV;
    float* At   = ws + OFF_AT;
    float* Bt   = ws + OFF_BT;
    float* bp   = ws + OFF_BP;
    float* ubuf = ws + OFF_U;
    float* vbuf = ws + OFF_V;
    int*   mc   = (int*)(ws + OFF_MC);
    int*   pe   = (int*)(ws + OFF_PE);
    int*   bh   = (int*)(ws + OFF_BH);
    int*   bc   = (int*)(ws + OFF_BC);
    int*   sS   = (int*)(ws + OFF_SS);
    int*   sD   = (int*)(ws + OFF_SD);
    float* sA   = ws + OFF_SA;
    int*   sP   = (int*)(ws + OFF_SP);
    float* pk   = ws + OFF_PK;
    float* gmA  = ws + OFF_GMA;
    float* gsA  = ws + OFF_GSA;
    float* grA  = ws + OFF_GRA;
    float* gmB  = ws + OFF_GMB;
    float* gsB  = ws + OFF_GSB;
    float* grB  = ws + OFF_GRB;
    float* hs   = ws + OFF_HS;
    float* cs   = ws + OFF_CS;

    hipMemsetAsync(d_ws, 0, (size_t)ZERO_END * sizeof(float), stream);

    k_lin0    <<<(NP*64 + 255)/256, 256, 0, stream>>>(x, l0w, l0b, out);
    k_patterns<<<1, 64, 0, stream>>>(e1w, e1b, bp, ubuf, vbuf, mc);
    k_AB2     <<<65*16, 256, 0, stream>>>(e2w, e2b, ubuf, vbuf, mc, At, Bt);
    k_eprep2  <<<NB_E, 256, 0, stream>>>(ei, ea, bp, mc, deg, pe, bh);
    k_scan2   <<<60, 256, 0, stream>>>(deg, dinv, bh, bc);
    k_scatter2<<<NB_E, 256, 0, stream>>>(ei, ea, pe, bc, sS, sD, sA, sP);
    k_wt2     <<<(7*4096 + 255)/256, 256, 0, stream>>>(rootw, gwhh, gwih, pk);

    for (int s = 0; s < 6; ++s) {
        k_edge4<<<EB, 256, 0, stream>>>(sS, sD, sA, sP, out, At, Bt, dinv, agg);
        k_gru8 <<<NP/16, 256, 0, stream>>>(out, agg, pk, convb, gbih, gbhh);
    }

    {
        void* args[] = {(void*)&swih, (void*)&swhh, (void*)&sbih, (void*)&sbhh,
                        (void*)&mwih, (void*)&mbih, (void*)&mbhh, (void*)&out,
                        (void*)&gmA, (void*)&gsA, (void*)&grA,
                        (void*)&gmB, (void*)&gsB, (void*)&grB,
                        (void*)&l1w, (void*)&l1b, (void*)&l3w, (void*)&l3b,
                        (void*)&dout};
        hipError_t err = hipLaunchCooperativeKernel(
            reinterpret_cast<void*>(k_s2s_all), dim3(256), dim3(512), args, 0, stream);
        if (err != hipSuccess) {
            // fallback: sequential launches
            for (int it = 0; it < 6; ++it) {
                float* gm_rd = (it & 1) ? gmA : gmB;
                float* gs_rd = (it & 1) ? gsA : gsB;
                float* gr_rd = (it & 1) ? grA : grB;
                float* gm_wr = (it & 1) ? gmB : gmA;
                float* gs_wr = (it & 1) ? gsB : gsA;
                float* gr_wr = (it & 1) ? grB : grA;
                k_s2s<<<256, 512, 0, stream>>>(swih, swhh, sbih, sbhh, hs, cs, out,
                                               gm_rd, gs_rd, gr_rd, gm_wr, gs_wr, gr_wr, it);
            }
            k_final2<<<1, 256, 0, stream>>>(mwih, mbih, mbhh, hs, gmB, gsB, grB,
                                            l1w, l1b, l3w, l3b, dout);
        }
    }
}

// Round 10
// 510.254 us; speedup vs baseline: 1.3925x; 1.3925x over previous
//
#include <hip/hip_runtime.h>
#include <math.h>

#define Nn 15000
#define NP 15008   // padded node count (gru tiles of 16, no bounds checks)
#define Ee 30000
#define NB_E 118   // ceil(Ee/256)
#define EB 938     // k_edge4 blocks (3752 waves x 8 edges)

// ---- workspace layout (float offsets) ----
// zero region (memset each call):
#define OFF_AGG   0          // [NP*64]
#define OFF_DEG   960512     // [Nn]
#define ZERO_END  975520
// written-before-read region:
#define OFF_OUT   975520     // [NP*64]
#define OFF_DINV  1936032    // [Nn]
#define OFF_AT    1951040    // [65*4096] transposed: At[p][o*64+i]
#define OFF_BT    2217280    // [65*4096]
#define OFF_BP    2483520    // [64]
#define OFF_U     2483584    // [65*64]
#define OFF_V     2487744    // [65*64]
#define OFF_MC    2491904    // [1] int
#define OFF_PE    2491920    // [Ee] int
#define OFF_BH    2521920    // [NB_E*65] int
#define OFF_BC    2529592    // [NB_E*65] int
#define OFF_SS    2537264    // [Ee] int
#define OFF_SD    2567264    // [Ee] int
#define OFF_SA    2597264    // [Ee] float
#define OFF_SP    2627264    // [Ee] int
#define OFF_PK    2657264    // [7*4096] packed GRU weights
#define OFF_GMA   2685936    // [256]
#define OFF_GSA   2686192    // [256]
#define OFF_GRA   2686448    // [256*64]
#define OFF_GMB   2702832    // [256]
#define OFF_GSB   2703088    // [256]
#define OFF_GRB   2703344    // [256*64]
#define OFF_HS    2719728    // [64]
#define OFF_CS    2719792    // [64]
// transposed Set2Set / mem LSTM weights (coalesced reads):
#define OFF_TSA   2719856    // [64*256] sa[i*256+g] = swih[g][i]+swhh[g][i]
#define OFF_TSB   2736240    // [64*256] sb[i*256+g] = swih[g][64+i]
#define OFF_TMA   2752624    // [64*256] ma[i*256+g] = mwih[g][i]
#define OFF_TMB   2769008    // [64*256] mb[i*256+g] = mwih[g][64+i]
#define WS_FLOATS 2785392

__device__ __forceinline__ float sigf(float x) { return 1.0f / (1.0f + expf(-x)); }
__device__ __forceinline__ float bcast(float v, int l) {
    return __int_as_float(__builtin_amdgcn_readlane(__float_as_int(v), l));
}
__device__ __forceinline__ int bcasti(int v, int l) {
    return __builtin_amdgcn_readlane(v, l);
}

// zero-padded: nodes [Nn, NP) get h = 0
__global__ void k_lin0(const float* __restrict__ x, const float* __restrict__ w,
                       const float* __restrict__ b, float* __restrict__ out) {
    int idx = blockIdx.x * 256 + threadIdx.x;
    if (idx >= NP * 64) return;
    int n = idx >> 6, o = idx & 63;
    float v = 0.f;
    if (n < Nn)
        v = fmaxf(b[o] + x[n*3+0]*w[o*3+0] + x[n*3+1]*w[o*3+1] + x[n*3+2]*w[o*3+2], 0.f);
    out[idx] = v;
}

// he[e,k] = relu(a*w1[k]+b1[k]) piecewise-linear in scalar a: <=64 breakpoints.
__global__ void k_patterns(const float* __restrict__ e1w, const float* __restrict__ e1b,
                           float* __restrict__ bp, float* __restrict__ u,
                           float* __restrict__ v, int* __restrict__ mc) {
    __shared__ float t[64]; __shared__ int valid[64]; __shared__ float sbp[65]; __shared__ int cnt;
    int k = threadIdx.x;
    float w1 = e1w[k], b1 = e1b[k];
    float tv = 0.f; int va = 0;
    if (w1 != 0.f) { tv = -b1 / w1; va = (tv > 0.f && tv < 1.f) ? 1 : 0; }
    t[k] = tv; valid[k] = va;
    __syncthreads();
    if (va) {
        int rank = 0;
        for (int kk = 0; kk < 64; ++kk)
            if (valid[kk] && (t[kk] < tv || (t[kk] == tv && kk < k))) rank++;
        sbp[rank] = tv;
    }
    if (k == 0) { int c = 0; for (int kk = 0; kk < 64; ++kk) c += valid[kk]; cnt = c; *mc = c; }
    __syncthreads();
    int m = cnt;
    if (k < m) bp[k] = sbp[k];
    for (int j = 0; j <= m; ++j) {
        float lo = (j == 0) ? 0.f : sbp[j-1];
        float hi = (j == m) ? 1.f : sbp[j];
        float c = 0.5f * (lo + hi);
        int msk = (c * w1 + b1) > 0.f;
        u[j*64 + k] = msk ? w1 : 0.f;
        v[j*64 + k] = msk ? b1 : 0.f;
    }
}

// parallel A/B build: grid 65x16
__global__ void k_AB2(const float* __restrict__ e2w, const float* __restrict__ e2b,
                      const float* __restrict__ u, const float* __restrict__ v,
                      const int* __restrict__ mc, float* __restrict__ At, float* __restrict__ Bt) {
    int j = blockIdx.x >> 4;
    if (j > *mc) return;
    int qc = blockIdx.x & 15;
    __shared__ float su[64], sv[64];
    if (threadIdx.x < 64) { su[threadIdx.x] = u[j*64+threadIdx.x]; sv[threadIdx.x] = v[j*64+threadIdx.x]; }
    __syncthreads();
    int q = qc*256 + threadIdx.x;
    int i = q >> 6, o = q & 63;
    const float* row = e2w + q*64;
    float a = 0.f, b = 0.f;
    #pragma unroll 8
    for (int k = 0; k < 64; ++k) { float w = row[k]; a = fmaf(su[k], w, a); b = fmaf(sv[k], w, b); }
    At[j*4096 + o*64 + i] = a;
    Bt[j*4096 + o*64 + i] = b + e2b[q];
}

__global__ void k_eprep2(const int* __restrict__ ei, const float* __restrict__ ea,
                         const float* __restrict__ bp, const int* __restrict__ mc,
                         float* __restrict__ deg, int* __restrict__ pe, int* __restrict__ bh) {
    __shared__ int lh[65];
    int tid = threadIdx.x;
    if (tid < 65) lh[tid] = 0;
    __syncthreads();
    int e = blockIdx.x * 256 + tid;
    if (e < Ee) {
        atomicAdd(&deg[ei[Ee + e]], 1.0f);
        float a = ea[e];
        int m = *mc, p = 0;
        for (int j = 0; j < m; ++j) p += (bp[j] <= a) ? 1 : 0;
        pe[e] = p;
        atomicAdd(&lh[p], 1);
    }
    __syncthreads();
    if (tid < 65) bh[blockIdx.x*65 + tid] = lh[tid];
}

__global__ void k_scan2(const float* __restrict__ deg, float* __restrict__ dinv,
                        const int* __restrict__ bh, int* __restrict__ bc) {
    int tid = threadIdx.x;
    if (blockIdx.x < 59) {
        int n = blockIdx.x * 256 + tid;
        if (n < Nn) dinv[n] = 1.0f / fmaxf(deg[n], 1.0f);
        return;
    }
    __shared__ int stot[65]; __shared__ int sbase[65];
    if (tid < 65) {
        int t = 0;
        for (int b = 0; b < NB_E; ++b) t += bh[b*65 + tid];
        stot[tid] = t;
    }
    __syncthreads();
    if (tid == 0) {
        int run = 0;
        for (int j = 0; j < 65; ++j) { sbase[j] = run; run += stot[j]; }
    }
    __syncthreads();
    if (tid < 65) {
        int run = sbase[tid];
        for (int b = 0; b < NB_E; ++b) { bc[b*65 + tid] = run; run += bh[b*65 + tid]; }
    }
}

__global__ void k_scatter2(const int* __restrict__ ei, const float* __restrict__ ea,
                           const int* __restrict__ pe, const int* __restrict__ bc,
                           int* __restrict__ sS, int* __restrict__ sD,
                           float* __restrict__ sA, int* __restrict__ sP) {
    __shared__ int cur[65];
    int tid = threadIdx.x;
    if (tid < 65) cur[tid] = bc[blockIdx.x*65 + tid];
    __syncthreads();
    int e = blockIdx.x * 256 + tid;
    if (e >= Ee) return;
    int p = pe[e];
    int pos = atomicAdd(&cur[p], 1);
    sS[pos] = ei[e]; sD[pos] = ei[Ee + e]; sA[pos] = ea[e]; sP[pos] = p;
}

// pk[g*4096 + i4*256 + lane*4 + k] = Wg[i4*4+k][lane]
__global__ void k_wt2(const float* __restrict__ rootw, const float* __restrict__ whh,
                      const float* __restrict__ wih, float* __restrict__ pk) {
    int idx = blockIdx.x * 256 + threadIdx.x;
    if (idx >= 7*4096) return;
    int g = idx >> 12;
    int t = idx & 4095;
    int q4 = t >> 2, k = t & 3;
    int lane = q4 & 63;
    int i4 = q4 >> 6;
    int i = i4*4 + k;
    float v;
    if (g == 0)      v = rootw[i*64 + lane];
    else if (g < 4)  v = whh[((g-1)*64 + lane)*64 + i];
    else             v = wih[((g-4)*64 + lane)*64 + i];
    pk[idx] = v;
}

// transposed Set2Set / mem LSTM weights for coalesced gate matvecs
__global__ void k_wt3(const float* __restrict__ swih, const float* __restrict__ swhh,
                      const float* __restrict__ mwih,
                      float* __restrict__ sa, float* __restrict__ sb,
                      float* __restrict__ ma, float* __restrict__ mb) {
    int idx = blockIdx.x * 256 + threadIdx.x;
    if (idx >= 4*16384) return;
    int t = idx >> 14, r = idx & 16383;
    int i = r >> 8, g = r & 255;
    if (t == 0)      sa[r] = swih[g*128 + i] + swhh[g*64 + i];
    else if (t == 1) sb[r] = swih[g*128 + 64 + i];
    else if (t == 2) ma[r] = mwih[g*128 + i];
    else             mb[r] = mwih[g*128 + 64 + i];
}

// pattern-sorted edges; chunk metadata lane-parallel; h-row pipelined one ahead.
__global__ __launch_bounds__(256) void k_edge4(
        const int* __restrict__ sS, const int* __restrict__ sD,
        const float* __restrict__ sA, const int* __restrict__ sP,
        const float* __restrict__ out, const float* __restrict__ At,
        const float* __restrict__ Bt, const float* __restrict__ dinv,
        float* __restrict__ agg) {
    int tid = threadIdx.x, lane = tid & 63;
    int wid = (blockIdx.x * 256 + tid) >> 6;
    const int CH = 8;
    int e0 = wid * CH;
    if (e0 >= Ee) return;
    int e1 = e0 + CH; if (e1 > Ee) e1 = Ee;
    int cnt = e1 - e0;

    int eidx = e0 + lane;
    int msrc = 0, mdst = 0, mp = 0; float ma = 0.f, mdv = 0.f;
    if (lane < cnt) {
        msrc = sS[eidx]; mdst = sD[eidx]; ma = sA[eidx]; mp = sP[eidx];
        mdv = dinv[mdst];
    }

    float Ar[64], Br[64];
    int curp = -1;
    float hv_next = out[bcasti(msrc, 0)*64 + lane];
    for (int j = 0; j < cnt; ++j) {
        float hv = hv_next;
        if (j+1 < cnt) hv_next = out[bcasti(msrc, j+1)*64 + lane];
        int p = bcasti(mp, j);
        if (p != curp) {
            curp = p;
            const float4* Ap4 = (const float4*)(At + p*4096 + lane*64);
            const float4* Bp4 = (const float4*)(Bt + p*4096 + lane*64);
            #pragma unroll
            for (int q = 0; q < 16; ++q) {
                float4 av = Ap4[q], bv = Bp4[q];
                Ar[q*4+0]=av.x; Ar[q*4+1]=av.y; Ar[q*4+2]=av.z; Ar[q*4+3]=av.w;
                Br[q*4+0]=bv.x; Br[q*4+1]=bv.y; Br[q*4+2]=bv.z; Br[q*4+3]=bv.w;
            }
        }
        float a = bcast(ma, j);
        float acc0 = 0.f, acc1 = 0.f;
        #pragma unroll
        for (int i = 0; i < 64; i += 2) {
            float h0 = bcast(hv, i);
            float h1 = bcast(hv, i+1);
            acc0 = fmaf(h0, fmaf(a, Ar[i],   Br[i]),   acc0);
            acc1 = fmaf(h1, fmaf(a, Ar[i+1], Br[i+1]), acc1);
        }
        float acc = (acc0 + acc1) * bcast(mdv, j);
        atomicAdd(&agg[bcasti(mdst, j)*64 + lane], acc);
    }
}

// fused NNConv-root + GRU: 4 waves x 2 gates, 16-node tile, weights VGPR-resident.
__global__ __launch_bounds__(256, 2) void k_gru8(
        float* __restrict__ out, float* __restrict__ agg,
        const float* __restrict__ pk, const float* __restrict__ convb,
        const float* __restrict__ gbih, const float* __restrict__ gbhh) {
    __shared__ float mL[1024];
    __shared__ float gA[1024];
    __shared__ float gB[1024];
    __shared__ float gC[1024];
    __shared__ float gD[1024];
    int tid = threadIdx.x, lane = tid & 63, w = tid >> 6;
    int pr = w >> 1, hf = w & 1;
    int n0 = blockIdx.x * 16;
    const float4* pk4 = (const float4*)pk;

    float4 wa[16], wb[16];
    {
        int g0 = pr*2, g1 = pr*2 + 1;
        #pragma unroll
        for (int i4 = 0; i4 < 16; ++i4) {
            wa[i4] = pk4[(g0*16 + i4)*64 + lane];
            wb[i4] = pk4[(g1*16 + i4)*64 + lane];
        }
    }
    float cbv = convb[lane];
    int nb0 = n0 + hf*8;

    #pragma unroll
    for (int nb = 0; nb < 8; nb += 4) {
        int n = nb0 + nb;
        float hv0 = out[(n+0)*64 + lane];
        float hv1 = out[(n+1)*64 + lane];
        float hv2 = out[(n+2)*64 + lane];
        float hv3 = out[(n+3)*64 + lane];
        float a0=0.f,a1=0.f,a2=0.f,a3=0.f, b0=0.f,b1=0.f,b2=0.f,b3=0.f;
        #pragma unroll
        for (int i4 = 0; i4 < 16; ++i4) {
            float4 va = wa[i4], vb = wb[i4];
            float h;
            h = bcast(hv0, i4*4+0); a0 = fmaf(h, va.x, a0); b0 = fmaf(h, vb.x, b0);
            h = bcast(hv1, i4*4+0); a1 = fmaf(h, va.x, a1); b1 = fmaf(h, vb.x, b1);
            h = bcast(hv2, i4*4+0); a2 = fmaf(h, va.x, a2); b2 = fmaf(h, vb.x, b2);
            h = bcast(hv3, i4*4+0); a3 = fmaf(h, va.x, a3); b3 = fmaf(h, vb.x, b3);
            h = bcast(hv0, i4*4+1); a0 = fmaf(h, va.y, a0); b0 = fmaf(h, vb.y, b0);
            h = bcast(hv1, i4*4+1); a1 = fmaf(h, va.y, a1); b1 = fmaf(h, vb.y, b1);
            h = bcast(hv2, i4*4+1); a2 = fmaf(h, va.y, a2); b2 = fmaf(h, vb.y, b2);
            h = bcast(hv3, i4*4+1); a3 = fmaf(h, va.y, a3); b3 = fmaf(h, vb.y, b3);
            h = bcast(hv0, i4*4+2); a0 = fmaf(h, va.z, a0); b0 = fmaf(h, vb.z, b0);
            h = bcast(hv1, i4*4+2); a1 = fmaf(h, va.z, a1); b1 = fmaf(h, vb.z, b1);
            h = bcast(hv2, i4*4+2); a2 = fmaf(h, va.z, a2); b2 = fmaf(h, vb.z, b2);
            h = bcast(hv3, i4*4+2); a3 = fmaf(h, va.z, a3); b3 = fmaf(h, vb.z, b3);
            h = bcast(hv0, i4*4+3); a0 = fmaf(h, va.w, a0); b0 = fmaf(h, vb.w, b0);
            h = bcast(hv1, i4*4+3); a1 = fmaf(h, va.w, a1); b1 = fmaf(h, vb.w, b1);
            h = bcast(hv2, i4*4+3); a2 = fmaf(h, va.w, a2); b2 = fmaf(h, vb.w, b2);
            h = bcast(hv3, i4*4+3); a3 = fmaf(h, va.w, a3); b3 = fmaf(h, vb.w, b3);
        }
        int ln = n - n0;
        float fa[4] = {a0,a1,a2,a3}, fb[4] = {b0,b1,b2,b3};
        if (pr == 0) {
            #pragma unroll
            for (int k2 = 0; k2 < 4; ++k2) {
                int gi = (n+k2)*64 + lane;
                float av = agg[gi]; agg[gi] = 0.f;
                mL[(ln+k2)*64 + lane] = fmaxf(fa[k2] + av + cbv, 0.f);
                gA[(ln+k2)*64 + lane] = fb[k2];
            }
        } else {
            #pragma unroll
            for (int k2 = 0; k2 < 4; ++k2) {
                gB[(ln+k2)*64 + lane] = fa[k2];
                gC[(ln+k2)*64 + lane] = fb[k2];
            }
        }
    }
    __syncthreads();

    if (pr == 0) {   // gi_r, gi_z
        #pragma unroll
        for (int i4 = 0; i4 < 16; ++i4) {
            wa[i4] = pk4[(4*16 + i4)*64 + lane];
            wb[i4] = pk4[(5*16 + i4)*64 + lane];
        }
        float br = gbih[lane]      + gbhh[lane];
        float bz = gbih[64+lane]   + gbhh[64+lane];
        #pragma unroll
        for (int nb = 0; nb < 8; nb += 4) {
            int ln = hf*8 + nb;
            float mv0 = mL[(ln+0)*64 + lane];
            float mv1 = mL[(ln+1)*64 + lane];
            float mv2 = mL[(ln+2)*64 + lane];
            float mv3 = mL[(ln+3)*64 + lane];
            float a0=0.f,a1=0.f,a2=0.f,a3=0.f, b0=0.f,b1=0.f,b2=0.f,b3=0.f;
            #pragma unroll
            for (int i4 = 0; i4 < 16; ++i4) {
                float4 va = wa[i4], vb = wb[i4];
                float h;
                h = bcast(mv0, i4*4+0); a0 = fmaf(h, va.x, a0); b0 = fmaf(h, vb.x, b0);
                h = bcast(mv1, i4*4+0); a1 = fmaf(h, va.x, a1); b1 = fmaf(h, vb.x, b1);
                h = bcast(mv2, i4*4+0); a2 = fmaf(h, va.x, a2); b2 = fmaf(h, vb.x, b2);
                h = bcast(mv3, i4*4+0); a3 = fmaf(h, va.x, a3); b3 = fmaf(h, vb.x, b3);
                h = bcast(mv0, i4*4+1); a0 = fmaf(h, va.y, a0); b0 = fmaf(h, vb.y, b0);
                h = bcast(mv1, i4*4+1); a1 = fmaf(h, va.y, a1); b1 = fmaf(h, vb.y, b1);
                h = bcast(mv2, i4*4+1); a2 = fmaf(h, va.y, a2); b2 = fmaf(h, vb.y, b2);
                h = bcast(mv3, i4*4+1); a3 = fmaf(h, va.y, a3); b3 = fmaf(h, vb.y, b3);
                h = bcast(mv0, i4*4+2); a0 = fmaf(h, va.z, a0); b0 = fmaf(h, vb.z, b0);
                h = bcast(mv1, i4*4+2); a1 = fmaf(h, va.z, a1); b1 = fmaf(h, vb.z, b1);
                h = bcast(mv2, i4*4+2); a2 = fmaf(h, va.z, a2); b2 = fmaf(h, vb.z, b2);
                h = bcast(mv3, i4*4+2); a3 = fmaf(h, va.z, a3); b3 = fmaf(h, vb.z, b3);
                h = bcast(mv0, i4*4+3); a0 = fmaf(h, va.w, a0); b0 = fmaf(h, vb.w, b0);
                h = bcast(mv1, i4*4+3); a1 = fmaf(h, va.w, a1); b1 = fmaf(h, vb.w, b1);
                h = bcast(mv2, i4*4+3); a2 = fmaf(h, va.w, a2); b2 = fmaf(h, vb.w, b2);
                h = bcast(mv3, i4*4+3); a3 = fmaf(h, va.w, a3); b3 = fmaf(h, vb.w, b3);
            }
            float fa[4] = {a0,a1,a2,a3}, fb[4] = {b0,b1,b2,b3};
            #pragma unroll
            for (int k2 = 0; k2 < 4; ++k2) {
                int r4 = (ln+k2)*64 + lane;
                gA[r4] = sigf(fa[k2] + gA[r4] + br);
                gB[r4] = sigf(fb[k2] + gB[r4] + bz);
            }
        }
    } else {        // gi_n
        #pragma unroll
        for (int i4 = 0; i4 < 16; ++i4) wa[i4] = pk4[(6*16 + i4)*64 + lane];
        float bn = gbih[128 + lane];
        #pragma unroll
        for (int nb = 0; nb < 8; nb += 4) {
            int ln = hf*8 + nb;
            float mv0 = mL[(ln+0)*64 + lane];
            float mv1 = mL[(ln+1)*64 + lane];
            float mv2 = mL[(ln+2)*64 + lane];
            float mv3 = mL[(ln+3)*64 + lane];
            float a0=0.f,a1=0.f,a2=0.f,a3=0.f;
            #pragma unroll
            for (int i4 = 0; i4 < 16; ++i4) {
                float4 va = wa[i4];
                float h;
                h = bcast(mv0, i4*4+0); a0 = fmaf(h, va.x, a0);
                h = bcast(mv1, i4*4+0); a1 = fmaf(h, va.x, a1);
                h = bcast(mv2, i4*4+0); a2 = fmaf(h, va.x, a2);
                h = bcast(mv3, i4*4+0); a3 = fmaf(h, va.x, a3);
                h = bcast(mv0, i4*4+1); a0 = fmaf(h, va.y, a0);
                h = bcast(mv1, i4*4+1); a1 = fmaf(h, va.y, a1);
                h = bcast(mv2, i4*4+1); a2 = fmaf(h, va.y, a2);
                h = bcast(mv3, i4*4+1); a3 = fmaf(h, va.y, a3);
                h = bcast(mv0, i4*4+2); a0 = fmaf(h, va.z, a0);
                h = bcast(mv1, i4*4+2); a1 = fmaf(h, va.z, a1);
                h = bcast(mv2, i4*4+2); a2 = fmaf(h, va.z, a2);
                h = bcast(mv3, i4*4+2); a3 = fmaf(h, va.z, a3);
                h = bcast(mv0, i4*4+3); a0 = fmaf(h, va.w, a0);
                h = bcast(mv1, i4*4+3); a1 = fmaf(h, va.w, a1);
                h = bcast(mv2, i4*4+3); a2 = fmaf(h, va.w, a2);
                h = bcast(mv3, i4*4+3); a3 = fmaf(h, va.w, a3);
            }
            float fa[4] = {a0,a1,a2,a3};
            #pragma unroll
            for (int k2 = 0; k2 < 4; ++k2)
                gD[(ln+k2)*64 + lane] = fa[k2] + bn;
        }
    }
    __syncthreads();

    float bhn = gbhh[128 + lane];
    #pragma unroll
    for (int p = 0; p < 4; ++p) {
        int ln = p*4 + w;
        int r4 = ln*64 + lane;
        int gi = (n0 + ln)*64 + lane;
        float r = gA[r4], z = gB[r4];
        float nn = tanhf(fmaf(r, gC[r4] + bhn, gD[r4]));
        float h = out[gi];
        out[gi] = (1.f - z)*nn + z*h;
    }
}

// Set2Set iteration: redundant finalize + LSTM (coalesced transposed weights),
// then online-softmax partials. Double-buffered partials (rd/wr).
__global__ __launch_bounds__(512) void k_s2s(
        const float* __restrict__ tsa, const float* __restrict__ tsb,
        const float* __restrict__ bih, const float* __restrict__ bhh,
        float* __restrict__ hs, float* __restrict__ cs,
        const float* __restrict__ out,
        const float* __restrict__ gmax_rd, const float* __restrict__ gsum_rd,
        const float* __restrict__ gr_rd,
        float* __restrict__ gmax_wr, float* __restrict__ gsum_wr,
        float* __restrict__ gr_wr, int it) {
    __shared__ float red[512], shs[64], scs[64], srv[64], sg[256];
    __shared__ float sm_m[8], sm_z[8], sm_r[8][64];
    int tid = threadIdx.x, lane = tid & 63, w = tid >> 6;
    if (it == 0) {
        if (tid < 64) { shs[tid] = 0.f; scs[tid] = 0.f; srv[tid] = 0.f; }
    } else {
        float gm = (tid < 256) ? gmax_rd[tid] : -3.4e38f;
        red[tid] = gm; __syncthreads();
        for (int s = 256; s > 0; s >>= 1) { if (tid < s) red[tid] = fmaxf(red[tid], red[tid+s]); __syncthreads(); }
        float M = red[0]; __syncthreads();
        red[tid] = (tid < 256) ? gsum_rd[tid] * expf(gm - M) : 0.f; __syncthreads();
        for (int s = 256; s > 0; s >>= 1) { if (tid < s) red[tid] += red[tid+s]; __syncthreads(); }
        float Z = red[0]; __syncthreads();
        float racc = 0.f;
        for (int b = w; b < 256; b += 8) racc = fmaf(gr_rd[b*64 + lane], expf(gmax_rd[b] - M), racc);
        red[tid] = racc; __syncthreads();
        if (w == 0) {
            float s = 0.f;
            #pragma unroll
            for (int k = 0; k < 8; ++k) s += red[k*64 + lane];
            srv[lane] = s / Z;
        }
        if (tid < 64) { shs[tid] = hs[tid]; scs[tid] = cs[tid]; }
    }
    __syncthreads();
    // LSTM gates via transposed tables: coalesced loads
    if (tid < 256) {
        float g = bih[tid] + bhh[tid];
        #pragma unroll 8
        for (int i = 0; i < 64; ++i)
            g += shs[i]*tsa[i*256 + tid] + srv[i]*tsb[i*256 + tid];
        sg[tid] = g;
    }
    __syncthreads();
    if (tid < 64) {
        float ii = sigf(sg[tid]), ff = sigf(sg[64+tid]);
        float gg = tanhf(sg[128+tid]), oo = sigf(sg[192+tid]);
        float c2 = ff*scs[tid] + ii*gg;
        float hn = oo*tanhf(c2);
        shs[tid] = hn;
        if (blockIdx.x == 0) { hs[tid] = hn; cs[tid] = c2; }
    }
    __syncthreads();
    float hsv = shs[lane];
    float m = -3.4e38f, Z2 = 0.f, racc2 = 0.f;
    for (int n = blockIdx.x*8 + w; n < Nn; n += 2048) {
        float ov = out[n*64 + lane];
        float p = ov * hsv;
        #pragma unroll
        for (int off = 32; off > 0; off >>= 1) p += __shfl_xor(p, off, 64);
        float mn = fmaxf(m, p);
        float sc = expf(m - mn);
        float t  = expf(p - mn);
        Z2 = fmaf(Z2, sc, t);
        racc2 = fmaf(racc2, sc, t*ov);
        m = mn;
    }
    if (lane == 0) { sm_m[w] = m; sm_z[w] = Z2; }
    sm_r[w][lane] = racc2;
    __syncthreads();
    if (w == 0) {
        float M = sm_m[0];
        #pragma unroll
        for (int j = 1; j < 8; ++j) M = fmaxf(M, sm_m[j]);
        float Zb = 0.f, rb = 0.f;
        #pragma unroll
        for (int j = 0; j < 8; ++j) {
            float e = expf(sm_m[j] - M);
            Zb = fmaf(sm_z[j], e, Zb);
            rb = fmaf(sm_r[j][lane], e, rb);
        }
        gr_wr[blockIdx.x*64 + lane] = rb;
        if (lane == 0) { gmax_wr[blockIdx.x] = M; gsum_wr[blockIdx.x] = Zb; }
    }
}

// final: finalize rv, mem-LSTM (h=c=0, transposed weights), lin1, lin3
__global__ __launch_bounds__(256) void k_final2(
        const float* __restrict__ tma, const float* __restrict__ tmb,
        const float* __restrict__ mbih, const float* __restrict__ mbhh,
        const float* __restrict__ hs,
        const float* __restrict__ gmax, const float* __restrict__ gsum,
        const float* __restrict__ gr,
        const float* __restrict__ l1w, const float* __restrict__ l1b,
        const float* __restrict__ l3w, const float* __restrict__ l3b,
        float* __restrict__ dout) {
    __shared__ float red[256], shs[64], srv[64], sg[256], shx[64], so[64];
    int tid = threadIdx.x, lane = tid & 63, w = tid >> 6;
    {
        float gm = gmax[tid];
        red[tid] = gm; __syncthreads();
        for (int s = 128; s > 0; s >>= 1) { if (tid < s) red[tid] = fmaxf(red[tid], red[tid+s]); __syncthreads(); }
        float M = red[0]; __syncthreads();
        red[tid] = gsum[tid] * expf(gm - M); __syncthreads();
        for (int s = 128; s > 0; s >>= 1) { if (tid < s) red[tid] += red[tid+s]; __syncthreads(); }
        float Z = red[0]; __syncthreads();
        float racc = 0.f;
        for (int b = w; b < 256; b += 4) racc = fmaf(gr[b*64 + lane], expf(gmax[b] - M), racc);
        red[tid] = racc; __syncthreads();
        if (w == 0) srv[lane] = (red[lane] + red[64+lane] + red[128+lane] + red[192+lane]) / Z;
        if (tid < 64) shs[tid] = hs[tid];
    }
    __syncthreads();
    {
        float g = mbih[tid] + mbhh[tid];
        #pragma unroll 8
        for (int i = 0; i < 64; ++i)
            g += shs[i]*tma[i*256 + tid] + srv[i]*tmb[i*256 + tid];
        sg[tid] = g;
    }
    __syncthreads();
    if (tid < 64) {
        float ii = sigf(sg[tid]);
        float gg = tanhf(sg[128+tid]);
        float oo = sigf(sg[192+tid]);
        float c2 = ii * gg;
        float hx = oo * tanhf(c2);
        shx[tid] = hx;
        dout[1 + tid] = hx;
        dout[65 + tid] = c2;
    }
    __syncthreads();
    if (tid < 64) {
        float a = l1b[tid];
        const float* wr = l1w + tid*64;
        #pragma unroll 8
        for (int i = 0; i < 64; ++i) a = fmaf(shx[i], wr[i], a);
        so[tid] = fmaxf(a, 0.f);
    }
    __syncthreads();
    if (tid == 0) {
        float v = l3b[0];
        for (int i = 0; i < 64; ++i) v = fmaf(so[i], l3w[i], v);
        dout[0] = v;
    }
}

extern "C" void kernel_launch(void* const* d_in, const int* in_sizes, int n_in,
                              void* d_out, int out_size, void* d_ws, size_t ws_size,
                              hipStream_t stream) {
    const float* x    = (const float*)d_in[0];
    const int*   ei   = (const int*)  d_in[1];
    const float* ea   = (const float*)d_in[2];
    const float* l0w  = (const float*)d_in[3];
    const float* l0b  = (const float*)d_in[4];
    const float* e1w  = (const float*)d_in[5];
    const float* e1b  = (const float*)d_in[6];
    const float* e2w  = (const float*)d_in[7];
    const float* e2b  = (const float*)d_in[8];
    const float* rootw= (const float*)d_in[9];
    const float* convb= (const float*)d_in[10];
    const float* gwih = (const float*)d_in[11];
    const float* gwhh = (const float*)d_in[12];
    const float* gbih = (const float*)d_in[13];
    const float* gbhh = (const float*)d_in[14];
    const float* swih = (const float*)d_in[15];
    const float* swhh = (const float*)d_in[16];
    const float* sbih = (const float*)d_in[17];
    const float* sbhh = (const float*)d_in[18];
    const float* mwih = (const float*)d_in[19];
    const float* mbih = (const float*)d_in[21];
    const float* mbhh = (const float*)d_in[22];
    const float* l1w  = (const float*)d_in[23];
    const float* l1b  = (const float*)d_in[24];
    const float* l3w  = (const float*)d_in[25];
    const float* l3b  = (const float*)d_in[26];

    float* ws   = (float*)d_ws;
    float* dout = (float*)d_out;
    if (ws_size < (size_t)WS_FLOATS * sizeof(float)) return;

    float* agg  = ws + OFF_AGG;
    float* deg  = ws + OFF_DEG;
    float* out  = ws + OFF_OUT;
    float* dinv = ws + OFF_DINV;
    float* At   = ws + OFF_AT;
    float* Bt   = ws + OFF_BT;
    float* bp   = ws + OFF_BP;
    float* ubuf = ws + OFF_U;
    float* vbuf = ws + OFF_V;
    int*   mc   = (int*)(ws + OFF_MC);
    int*   pe   = (int*)(ws + OFF_PE);
    int*   bh   = (int*)(ws + OFF_BH);
    int*   bc   = (int*)(ws + OFF_BC);
    int*   sS   = (int*)(ws + OFF_SS);
    int*   sD   = (int*)(ws + OFF_SD);
    float* sA   = ws + OFF_SA;
    int*   sP   = (int*)(ws + OFF_SP);
    float* pk   = ws + OFF_PK;
    float* gmA  = ws + OFF_GMA;
    float* gsA  = ws + OFF_GSA;
    float* grA  = ws + OFF_GRA;
    float* gmB  = ws + OFF_GMB;
    float* gsB  = ws + OFF_GSB;
    float* grB  = ws + OFF_GRB;
    float* hs   = ws + OFF_HS;
    float* cs   = ws + OFF_CS;
    float* tsa  = ws + OFF_TSA;
    float* tsb  = ws + OFF_TSB;
    float* tma  = ws + OFF_TMA;
    float* tmb  = ws + OFF_TMB;

    hipMemsetAsync(d_ws, 0, (size_t)ZERO_END * sizeof(float), stream);

    k_lin0    <<<(NP*64 + 255)/256, 256, 0, stream>>>(x, l0w, l0b, out);
    k_patterns<<<1, 64, 0, stream>>>(e1w, e1b, bp, ubuf, vbuf, mc);
    k_AB2     <<<65*16, 256, 0, stream>>>(e2w, e2b, ubuf, vbuf, mc, At, Bt);
    k_eprep2  <<<NB_E, 256, 0, stream>>>(ei, ea, bp, mc, deg, pe, bh);
    k_scan2   <<<60, 256, 0, stream>>>(deg, dinv, bh, bc);
    k_scatter2<<<NB_E, 256, 0, stream>>>(ei, ea, pe, bc, sS, sD, sA, sP);
    k_wt2     <<<(7*4096 + 255)/256, 256, 0, stream>>>(rootw, gwhh, gwih, pk);
    k_wt3     <<<(4*16384 + 255)/256, 256, 0, stream>>>(swih, swhh, mwih, tsa, tsb, tma, tmb);

    for (int s = 0; s < 6; ++s) {
        k_edge4<<<EB, 256, 0, stream>>>(sS, sD, sA, sP, out, At, Bt, dinv, agg);
        k_gru8 <<<NP/16, 256, 0, stream>>>(out, agg, pk, convb, gbih, gbhh);
    }

    for (int it = 0; it < 6; ++it) {
        float* gm_rd = (it & 1) ? gmA : gmB;   // unused at it=0
        float* gs_rd = (it & 1) ? gsA : gsB;
        float* gr_rd = (it & 1) ? grA : grB;
        float* gm_wr = (it & 1) ? gmB : gmA;
        float* gs_wr = (it & 1) ? gsB : gsA;
        float* gr_wr = (it & 1) ? grB : grA;
        k_s2s<<<256, 512, 0, stream>>>(tsa, tsb, sbih, sbhh, hs, cs, out,
                                       gm_rd, gs_rd, gr_rd, gm_wr, gs_wr, gr_wr, it);
    }

    // it=5 wrote the B buffers
    k_final2<<<1, 256, 0, stream>>>(tma, tmb, mbih, mbhh, hs, gmB, gsB, grB,
                                    l1w, l1b, l3w, l3b, dout);
}

// Round 11
// 453.204 us; speedup vs baseline: 1.5678x; 1.1259x over previous
//
#include <hip/hip_runtime.h>
#include <math.h>

#define Nn 15000
#define NP 15040   // padded node count (64-node gru tiles, no bounds checks)
#define Ee 30000
#define NB_E 118   // ceil(Ee/256)
#define EB 938     // k_edge4 blocks (3752 waves x 8 edges)

// ---- workspace layout (float offsets) ----
// zero region (memset each call):
#define OFF_AGG   0          // [NP*64]
#define OFF_DEG   962560     // [Nn]
#define ZERO_END  977560
// written-before-read region:
#define OFF_OUT   977568     // [NP*64]
#define OFF_DINV  1940128    // [Nn]
#define OFF_AT    1955136    // [65*4096] transposed: At[p][o*64+i]
#define OFF_BT    2221376    // [65*4096]
#define OFF_BP    2487616    // [64]
#define OFF_U     2487680    // [65*64]
#define OFF_V     2491840    // [65*64]
#define OFF_MC    2496000    // [1] int
#define OFF_PE    2496016    // [Ee] int
#define OFF_BH    2526016    // [NB_E*65] int
#define OFF_BC    2533696    // [NB_E*65] int
#define OFF_SS    2541376    // [Ee] int
#define OFF_SD    2571376    // [Ee] int
#define OFF_SA    2601376    // [Ee] float
#define OFF_SP    2631376    // [Ee] int
#define OFF_PK    2661376    // [7*4096] packed GRU weights
#define OFF_GMA   2690048    // [256]
#define OFF_GSA   2690304    // [256]
#define OFF_GRA   2690560    // [256*64]
#define OFF_GMB   2706944    // [256]
#define OFF_GSB   2707200    // [256]
#define OFF_GRB   2707456    // [256*64]
#define OFF_HS    2723840    // [64]
#define OFF_CS    2723904    // [64]
// transposed Set2Set / mem LSTM weights (coalesced reads):
#define OFF_TSA   2723968    // [64*256] sa[i*256+g] = swih[g][i]+swhh[g][i]
#define OFF_TSB   2740352    // [64*256] sb[i*256+g] = swih[g][64+i]
#define OFF_TMA   2756736    // [64*256] ma[i*256+g] = mwih[g][i]
#define OFF_TMB   2773120    // [64*256] mb[i*256+g] = mwih[g][64+i]
#define WS_FLOATS 2789504

__device__ __forceinline__ float sigf(float x) { return 1.0f / (1.0f + expf(-x)); }
__device__ __forceinline__ float bcast(float v, int l) {
    return __int_as_float(__builtin_amdgcn_readlane(__float_as_int(v), l));
}
__device__ __forceinline__ int bcasti(int v, int l) {
    return __builtin_amdgcn_readlane(v, l);
}

// zero-padded: nodes [Nn, NP) get h = 0
__global__ void k_lin0(const float* __restrict__ x, const float* __restrict__ w,
                       const float* __restrict__ b, float* __restrict__ out) {
    int idx = blockIdx.x * 256 + threadIdx.x;
    if (idx >= NP * 64) return;
    int n = idx >> 6, o = idx & 63;
    float v = 0.f;
    if (n < Nn)
        v = fmaxf(b[o] + x[n*3+0]*w[o*3+0] + x[n*3+1]*w[o*3+1] + x[n*3+2]*w[o*3+2], 0.f);
    out[idx] = v;
}

// he[e,k] = relu(a*w1[k]+b1[k]) piecewise-linear in scalar a: <=64 breakpoints.
__global__ void k_patterns(const float* __restrict__ e1w, const float* __restrict__ e1b,
                           float* __restrict__ bp, float* __restrict__ u,
                           float* __restrict__ v, int* __restrict__ mc) {
    __shared__ float t[64]; __shared__ int valid[64]; __shared__ float sbp[65]; __shared__ int cnt;
    int k = threadIdx.x;
    float w1 = e1w[k], b1 = e1b[k];
    float tv = 0.f; int va = 0;
    if (w1 != 0.f) { tv = -b1 / w1; va = (tv > 0.f && tv < 1.f) ? 1 : 0; }
    t[k] = tv; valid[k] = va;
    __syncthreads();
    if (va) {
        int rank = 0;
        for (int kk = 0; kk < 64; ++kk)
            if (valid[kk] && (t[kk] < tv || (t[kk] == tv && kk < k))) rank++;
        sbp[rank] = tv;
    }
    if (k == 0) { int c = 0; for (int kk = 0; kk < 64; ++kk) c += valid[kk]; cnt = c; *mc = c; }
    __syncthreads();
    int m = cnt;
    if (k < m) bp[k] = sbp[k];
    for (int j = 0; j <= m; ++j) {
        float lo = (j == 0) ? 0.f : sbp[j-1];
        float hi = (j == m) ? 1.f : sbp[j];
        float c = 0.5f * (lo + hi);
        int msk = (c * w1 + b1) > 0.f;
        u[j*64 + k] = msk ? w1 : 0.f;
        v[j*64 + k] = msk ? b1 : 0.f;
    }
}

// parallel A/B build: grid 65x16
__global__ void k_AB2(const float* __restrict__ e2w, const float* __restrict__ e2b,
                      const float* __restrict__ u, const float* __restrict__ v,
                      const int* __restrict__ mc, float* __restrict__ At, float* __restrict__ Bt) {
    int j = blockIdx.x >> 4;
    if (j > *mc) return;
    int qc = blockIdx.x & 15;
    __shared__ float su[64], sv[64];
    if (threadIdx.x < 64) { su[threadIdx.x] = u[j*64+threadIdx.x]; sv[threadIdx.x] = v[j*64+threadIdx.x]; }
    __syncthreads();
    int q = qc*256 + threadIdx.x;
    int i = q >> 6, o = q & 63;
    const float* row = e2w + q*64;
    float a = 0.f, b = 0.f;
    #pragma unroll 8
    for (int k = 0; k < 64; ++k) { float w = row[k]; a = fmaf(su[k], w, a); b = fmaf(sv[k], w, b); }
    At[j*4096 + o*64 + i] = a;
    Bt[j*4096 + o*64 + i] = b + e2b[q];
}

__global__ void k_eprep2(const int* __restrict__ ei, const float* __restrict__ ea,
                         const float* __restrict__ bp, const int* __restrict__ mc,
                         float* __restrict__ deg, int* __restrict__ pe, int* __restrict__ bh) {
    __shared__ int lh[65];
    int tid = threadIdx.x;
    if (tid < 65) lh[tid] = 0;
    __syncthreads();
    int e = blockIdx.x * 256 + tid;
    if (e < Ee) {
        atomicAdd(&deg[ei[Ee + e]], 1.0f);
        float a = ea[e];
        int m = *mc, p = 0;
        for (int j = 0; j < m; ++j) p += (bp[j] <= a) ? 1 : 0;
        pe[e] = p;
        atomicAdd(&lh[p], 1);
    }
    __syncthreads();
    if (tid < 65) bh[blockIdx.x*65 + tid] = lh[tid];
}

__global__ void k_scan2(const float* __restrict__ deg, float* __restrict__ dinv,
                        const int* __restrict__ bh, int* __restrict__ bc) {
    int tid = threadIdx.x;
    if (blockIdx.x < 59) {
        int n = blockIdx.x * 256 + tid;
        if (n < Nn) dinv[n] = 1.0f / fmaxf(deg[n], 1.0f);
        return;
    }
    __shared__ int stot[65]; __shared__ int sbase[65];
    if (tid < 65) {
        int t = 0;
        for (int b = 0; b < NB_E; ++b) t += bh[b*65 + tid];
        stot[tid] = t;
    }
    __syncthreads();
    if (tid == 0) {
        int run = 0;
        for (int j = 0; j < 65; ++j) { sbase[j] = run; run += stot[j]; }
    }
    __syncthreads();
    if (tid < 65) {
        int run = sbase[tid];
        for (int b = 0; b < NB_E; ++b) { bc[b*65 + tid] = run; run += bh[b*65 + tid]; }
    }
}

__global__ void k_scatter2(const int* __restrict__ ei, const float* __restrict__ ea,
                           const int* __restrict__ pe, const int* __restrict__ bc,
                           int* __restrict__ sS, int* __restrict__ sD,
                           float* __restrict__ sA, int* __restrict__ sP) {
    __shared__ int cur[65];
    int tid = threadIdx.x;
    if (tid < 65) cur[tid] = bc[blockIdx.x*65 + tid];
    __syncthreads();
    int e = blockIdx.x * 256 + tid;
    if (e >= Ee) return;
    int p = pe[e];
    int pos = atomicAdd(&cur[p], 1);
    sS[pos] = ei[e]; sD[pos] = ei[Ee + e]; sA[pos] = ea[e]; sP[pos] = p;
}

// pk[g*4096 + i4*256 + lane*4 + k] = Wg[i4*4+k][lane]
// g: 0=root; 1..3 whh gates r,z,n; 4..6 wih gates r,z,n
__global__ void k_wt2(const float* __restrict__ rootw, const float* __restrict__ whh,
                      const float* __restrict__ wih, float* __restrict__ pk) {
    int idx = blockIdx.x * 256 + threadIdx.x;
    if (idx >= 7*4096) return;
    int g = idx >> 12;
    int t = idx & 4095;
    int q4 = t >> 2, k = t & 3;
    int lane = q4 & 63;
    int i4 = q4 >> 6;
    int i = i4*4 + k;
    float v;
    if (g == 0)      v = rootw[i*64 + lane];
    else if (g < 4)  v = whh[((g-1)*64 + lane)*64 + i];
    else             v = wih[((g-4)*64 + lane)*64 + i];
    pk[idx] = v;
}

// transposed Set2Set / mem LSTM weights for coalesced gate matvecs
__global__ void k_wt3(const float* __restrict__ swih, const float* __restrict__ swhh,
                      const float* __restrict__ mwih,
                      float* __restrict__ sa, float* __restrict__ sb,
                      float* __restrict__ ma, float* __restrict__ mb) {
    int idx = blockIdx.x * 256 + threadIdx.x;
    if (idx >= 4*16384) return;
    int t = idx >> 14, r = idx & 16383;
    int i = r >> 8, g = r & 255;
    if (t == 0)      sa[r] = swih[g*128 + i] + swhh[g*64 + i];
    else if (t == 1) sb[r] = swih[g*128 + 64 + i];
    else if (t == 2) ma[r] = mwih[g*128 + i];
    else             mb[r] = mwih[g*128 + 64 + i];
}

// pattern-sorted edges; chunk metadata lane-parallel; h-row pipelined one ahead.
__global__ __launch_bounds__(256) void k_edge4(
        const int* __restrict__ sS, const int* __restrict__ sD,
        const float* __restrict__ sA, const int* __restrict__ sP,
        const float* __restrict__ out, const float* __restrict__ At,
        const float* __restrict__ Bt, const float* __restrict__ dinv,
        float* __restrict__ agg) {
    int tid = threadIdx.x, lane = tid & 63;
    int wid = (blockIdx.x * 256 + tid) >> 6;
    const int CH = 8;
    int e0 = wid * CH;
    if (e0 >= Ee) return;
    int e1 = e0 + CH; if (e1 > Ee) e1 = Ee;
    int cnt = e1 - e0;

    int eidx = e0 + lane;
    int msrc = 0, mdst = 0, mp = 0; float ma = 0.f, mdv = 0.f;
    if (lane < cnt) {
        msrc = sS[eidx]; mdst = sD[eidx]; ma = sA[eidx]; mp = sP[eidx];
        mdv = dinv[mdst];
    }

    float Ar[64], Br[64];
    int curp = -1;
    float hv_next = out[bcasti(msrc, 0)*64 + lane];
    for (int j = 0; j < cnt; ++j) {
        float hv = hv_next;
        if (j+1 < cnt) hv_next = out[bcasti(msrc, j+1)*64 + lane];
        int p = bcasti(mp, j);
        if (p != curp) {
            curp = p;
            const float4* Ap4 = (const float4*)(At + p*4096 + lane*64);
            const float4* Bp4 = (const float4*)(Bt + p*4096 + lane*64);
            #pragma unroll
            for (int q = 0; q < 16; ++q) {
                float4 av = Ap4[q], bv = Bp4[q];
                Ar[q*4+0]=av.x; Ar[q*4+1]=av.y; Ar[q*4+2]=av.z; Ar[q*4+3]=av.w;
                Br[q*4+0]=bv.x; Br[q*4+1]=bv.y; Br[q*4+2]=bv.z; Br[q*4+3]=bv.w;
            }
        }
        float a = bcast(ma, j);
        float acc0 = 0.f, acc1 = 0.f;
        #pragma unroll
        for (int i = 0; i < 64; i += 2) {
            float h0 = bcast(hv, i);
            float h1 = bcast(hv, i+1);
            acc0 = fmaf(h0, fmaf(a, Ar[i],   Br[i]),   acc0);
            acc1 = fmaf(h1, fmaf(a, Ar[i+1], Br[i+1]), acc1);
        }
        float acc = (acc0 + acc1) * bcast(mdv, j);
        atomicAdd(&agg[bcasti(mdst, j)*64 + lane], acc);
    }
}

// fused NNConv-root + GRU: all 7 weight matrices staged in LDS (112KB,
// guaranteed resident — the compiler refuses VGPR residency), one wave owns
// 8 nodes end-to-end (h/m/gh in registers, readlane broadcast, no gate LDS,
// single barrier). 512 thr / 64-node tile / 235 blocks ~= 1 generation.
__global__ __launch_bounds__(512, 2) void k_gru9(
        float* __restrict__ out, float* __restrict__ agg,
        const float* __restrict__ pk, const float* __restrict__ convb,
        const float* __restrict__ gbih, const float* __restrict__ gbhh) {
    __shared__ __align__(16) float wL[7*4096];   // 112 KB
    int tid = threadIdx.x, lane = tid & 63, w = tid >> 6;
    {
        const float4* src = (const float4*)pk;
        float4* dst = (float4*)wL;
        #pragma unroll
        for (int i = 0; i < 14; ++i) dst[i*512 + tid] = src[i*512 + tid];
    }
    __syncthreads();
    const float4* wL4 = (const float4*)wL;
    int n0 = blockIdx.x*64 + w*8;

    float hv[8], mv[8], ghr[8], ghz[8], ghn[8];
    #pragma unroll
    for (int k = 0; k < 8; ++k) hv[k] = out[(n0+k)*64 + lane];

    // ---- phase A: root, gh_r, gh_z, gh_n ----
    float a0[8], a1[8], a2[8], a3[8];
    #pragma unroll
    for (int k = 0; k < 8; ++k) { a0[k]=0.f; a1[k]=0.f; a2[k]=0.f; a3[k]=0.f; }
    #pragma unroll 4
    for (int i4 = 0; i4 < 16; ++i4) {
        float4 w0 = wL4[(0*16+i4)*64 + lane];
        float4 w1 = wL4[(1*16+i4)*64 + lane];
        float4 w2 = wL4[(2*16+i4)*64 + lane];
        float4 w3 = wL4[(3*16+i4)*64 + lane];
        #pragma unroll
        for (int k = 0; k < 8; ++k) {
            float h;
            h = bcast(hv[k], i4*4+0);
            a0[k]=fmaf(h,w0.x,a0[k]); a1[k]=fmaf(h,w1.x,a1[k]);
            a2[k]=fmaf(h,w2.x,a2[k]); a3[k]=fmaf(h,w3.x,a3[k]);
            h = bcast(hv[k], i4*4+1);
            a0[k]=fmaf(h,w0.y,a0[k]); a1[k]=fmaf(h,w1.y,a1[k]);
            a2[k]=fmaf(h,w2.y,a2[k]); a3[k]=fmaf(h,w3.y,a3[k]);
            h = bcast(hv[k], i4*4+2);
            a0[k]=fmaf(h,w0.z,a0[k]); a1[k]=fmaf(h,w1.z,a1[k]);
            a2[k]=fmaf(h,w2.z,a2[k]); a3[k]=fmaf(h,w3.z,a3[k]);
            h = bcast(hv[k], i4*4+3);
            a0[k]=fmaf(h,w0.w,a0[k]); a1[k]=fmaf(h,w1.w,a1[k]);
            a2[k]=fmaf(h,w2.w,a2[k]); a3[k]=fmaf(h,w3.w,a3[k]);
        }
    }
    // m = relu(root + agg + convb); keep gh_* in regs; zero agg
    float cbv = convb[lane];
    #pragma unroll
    for (int k = 0; k < 8; ++k) {
        int gi = (n0+k)*64 + lane;
        float av = agg[gi]; agg[gi] = 0.f;
        mv[k] = fmaxf(a0[k] + av + cbv, 0.f);
        ghr[k] = a1[k]; ghz[k] = a2[k]; ghn[k] = a3[k];
    }

    // ---- phase B: gi_r, gi_z, gi_n (from m) ----
    #pragma unroll
    for (int k = 0; k < 8; ++k) { a0[k]=0.f; a1[k]=0.f; a2[k]=0.f; }
    #pragma unroll 4
    for (int i4 = 0; i4 < 16; ++i4) {
        float4 w4v = wL4[(4*16+i4)*64 + lane];
        float4 w5v = wL4[(5*16+i4)*64 + lane];
        float4 w6v = wL4[(6*16+i4)*64 + lane];
        #pragma unroll
        for (int k = 0; k < 8; ++k) {
            float h;
            h = bcast(mv[k], i4*4+0);
            a0[k]=fmaf(h,w4v.x,a0[k]); a1[k]=fmaf(h,w5v.x,a1[k]); a2[k]=fmaf(h,w6v.x,a2[k]);
            h = bcast(mv[k], i4*4+1);
            a0[k]=fmaf(h,w4v.y,a0[k]); a1[k]=fmaf(h,w5v.y,a1[k]); a2[k]=fmaf(h,w6v.y,a2[k]);
            h = bcast(mv[k], i4*4+2);
            a0[k]=fmaf(h,w4v.z,a0[k]); a1[k]=fmaf(h,w5v.z,a1[k]); a2[k]=fmaf(h,w6v.z,a2[k]);
            h = bcast(mv[k], i4*4+3);
            a0[k]=fmaf(h,w4v.w,a0[k]); a1[k]=fmaf(h,w5v.w,a1[k]); a2[k]=fmaf(h,w6v.w,a2[k]);
        }
    }

    // ---- combine ----
    float br  = gbih[lane]      + gbhh[lane];
    float bz  = gbih[64+lane]   + gbhh[64+lane];
    float bnI = gbih[128+lane];
    float bnH = gbhh[128+lane];
    #pragma unroll
    for (int k = 0; k < 8; ++k) {
        float r  = sigf(a0[k] + ghr[k] + br);
        float z  = sigf(a1[k] + ghz[k] + bz);
        float nn = tanhf(fmaf(r, ghn[k] + bnH, a2[k] + bnI));
        out[(n0+k)*64 + lane] = (1.f - z)*nn + z*hv[k];
    }
}

// Set2Set iteration: redundant finalize + LSTM (coalesced transposed weights),
// then online-softmax partials. Double-buffered partials (rd/wr).
__global__ __launch_bounds__(512) void k_s2s(
        const float* __restrict__ tsa, const float* __restrict__ tsb,
        const float* __restrict__ bih, const float* __restrict__ bhh,
        float* __restrict__ hs, float* __restrict__ cs,
        const float* __restrict__ out,
        const float* __restrict__ gmax_rd, const float* __restrict__ gsum_rd,
        const float* __restrict__ gr_rd,
        float* __restrict__ gmax_wr, float* __restrict__ gsum_wr,
        float* __restrict__ gr_wr, int it) {
    __shared__ float red[512], shs[64], scs[64], srv[64], sg[256];
    __shared__ float sm_m[8], sm_z[8], sm_r[8][64];
    int tid = threadIdx.x, lane = tid & 63, w = tid >> 6;
    if (it == 0) {
        if (tid < 64) { shs[tid] = 0.f; scs[tid] = 0.f; srv[tid] = 0.f; }
    } else {
        float gm = (tid < 256) ? gmax_rd[tid] : -3.4e38f;
        red[tid] = gm; __syncthreads();
        for (int s = 256; s > 0; s >>= 1) { if (tid < s) red[tid] = fmaxf(red[tid], red[tid+s]); __syncthreads(); }
        float M = red[0]; __syncthreads();
        red[tid] = (tid < 256) ? gsum_rd[tid] * expf(gm - M) : 0.f; __syncthreads();
        for (int s = 256; s > 0; s >>= 1) { if (tid < s) red[tid] += red[tid+s]; __syncthreads(); }
        float Z = red[0]; __syncthreads();
        float racc = 0.f;
        for (int b = w; b < 256; b += 8) racc = fmaf(gr_rd[b*64 + lane], expf(gmax_rd[b] - M), racc);
        red[tid] = racc; __syncthreads();
        if (w == 0) {
            float s = 0.f;
            #pragma unroll
            for (int k = 0; k < 8; ++k) s += red[k*64 + lane];
            srv[lane] = s / Z;
        }
        if (tid < 64) { shs[tid] = hs[tid]; scs[tid] = cs[tid]; }
    }
    __syncthreads();
    // LSTM gates via transposed tables: coalesced loads
    if (tid < 256) {
        float g = bih[tid] + bhh[tid];
        #pragma unroll 8
        for (int i = 0; i < 64; ++i)
            g += shs[i]*tsa[i*256 + tid] + srv[i]*tsb[i*256 + tid];
        sg[tid] = g;
    }
    __syncthreads();
    if (tid < 64) {
        float ii = sigf(sg[tid]), ff = sigf(sg[64+tid]);
        float gg = tanhf(sg[128+tid]), oo = sigf(sg[192+tid]);
        float c2 = ff*scs[tid] + ii*gg;
        float hn = oo*tanhf(c2);
        shs[tid] = hn;
        if (blockIdx.x == 0) { hs[tid] = hn; cs[tid] = c2; }
    }
    __syncthreads();
    float hsv = shs[lane];
    float m = -3.4e38f, Z2 = 0.f, racc2 = 0.f;
    for (int n = blockIdx.x*8 + w; n < Nn; n += 2048) {
        float ov = out[n*64 + lane];
        float p = ov * hsv;
        #pragma unroll
        for (int off = 32; off > 0; off >>= 1) p += __shfl_xor(p, off, 64);
        float mn = fmaxf(m, p);
        float sc = expf(m - mn);
        float t  = expf(p - mn);
        Z2 = fmaf(Z2, sc, t);
        racc2 = fmaf(racc2, sc, t*ov);
        m = mn;
    }
    if (lane == 0) { sm_m[w] = m; sm_z[w] = Z2; }
    sm_r[w][lane] = racc2;
    __syncthreads();
    if (w == 0) {
        float M = sm_m[0];
        #pragma unroll
        for (int j = 1; j < 8; ++j) M = fmaxf(M, sm_m[j]);
        float Zb = 0.f, rb = 0.f;
        #pragma unroll
        for (int j = 0; j < 8; ++j) {
            float e = expf(sm_m[j] - M);
            Zb = fmaf(sm_z[j], e, Zb);
            rb = fmaf(sm_r[j][lane], e, rb);
        }
        gr_wr[blockIdx.x*64 + lane] = rb;
        if (lane == 0) { gmax_wr[blockIdx.x] = M; gsum_wr[blockIdx.x] = Zb; }
    }
}

// final: finalize rv, mem-LSTM (h=c=0, transposed weights), lin1, lin3
__global__ __launch_bounds__(256) void k_final2(
        const float* __restrict__ tma, const float* __restrict__ tmb,
        const float* __restrict__ mbih, const float* __restrict__ mbhh,
        const float* __restrict__ hs,
        const float* __restrict__ gmax, const float* __restrict__ gsum,
        const float* __restrict__ gr,
        const float* __restrict__ l1w, const float* __restrict__ l1b,
        const float* __restrict__ l3w, const float* __restrict__ l3b,
        float* __restrict__ dout) {
    __shared__ float red[256], shs[64], srv[64], sg[256], shx[64], so[64];
    int tid = threadIdx.x, lane = tid & 63, w = tid >> 6;
    {
        float gm = gmax[tid];
        red[tid] = gm; __syncthreads();
        for (int s = 128; s > 0; s >>= 1) { if (tid < s) red[tid] = fmaxf(red[tid], red[tid+s]); __syncthreads(); }
        float M = red[0]; __syncthreads();
        red[tid] = gsum[tid] * expf(gm - M); __syncthreads();
        for (int s = 128; s > 0; s >>= 1) { if (tid < s) red[tid] += red[tid+s]; __syncthreads(); }
        float Z = red[0]; __syncthreads();
        float racc = 0.f;
        for (int b = w; b < 256; b += 4) racc = fmaf(gr[b*64 + lane], expf(gmax[b] - M), racc);
        red[tid] = racc; __syncthreads();
        if (w == 0) srv[lane] = (red[lane] + red[64+lane] + red[128+lane] + red[192+lane]) / Z;
        if (tid < 64) shs[tid] = hs[tid];
    }
    __syncthreads();
    {
        float g = mbih[tid] + mbhh[tid];
        #pragma unroll 8
        for (int i = 0; i < 64; ++i)
            g += shs[i]*tma[i*256 + tid] + srv[i]*tmb[i*256 + tid];
        sg[tid] = g;
    }
    __syncthreads();
    if (tid < 64) {
        float ii = sigf(sg[tid]);
        float gg = tanhf(sg[128+tid]);
        float oo = sigf(sg[192+tid]);
        float c2 = ii * gg;
        float hx = oo * tanhf(c2);
        shx[tid] = hx;
        dout[1 + tid] = hx;
        dout[65 + tid] = c2;
    }
    __syncthreads();
    if (tid < 64) {
        float a = l1b[tid];
        const float* wr = l1w + tid*64;
        #pragma unroll 8
        for (int i = 0; i < 64; ++i) a = fmaf(shx[i], wr[i], a);
        so[tid] = fmaxf(a, 0.f);
    }
    __syncthreads();
    if (tid == 0) {
        float v = l3b[0];
        for (int i = 0; i < 64; ++i) v = fmaf(so[i], l3w[i], v);
        dout[0] = v;
    }
}

extern "C" void kernel_launch(void* const* d_in, const int* in_sizes, int n_in,
                              void* d_out, int out_size, void* d_ws, size_t ws_size,
                              hipStream_t stream) {
    const float* x    = (const float*)d_in[0];
    const int*   ei   = (const int*)  d_in[1];
    const float* ea   = (const float*)d_in[2];
    const float* l0w  = (const float*)d_in[3];
    const float* l0b  = (const float*)d_in[4];
    const float* e1w  = (const float*)d_in[5];
    const float* e1b  = (const float*)d_in[6];
    const float* e2w  = (const float*)d_in[7];
    const float* e2b  = (const float*)d_in[8];
    const float* rootw= (const float*)d_in[9];
    const float* convb= (const float*)d_in[10];
    const float* gwih = (const float*)d_in[11];
    const float* gwhh = (const float*)d_in[12];
    const float* gbih = (const float*)d_in[13];
    const float* gbhh = (const float*)d_in[14];
    const float* swih = (const float*)d_in[15];
    const float* swhh = (const float*)d_in[16];
    const float* sbih = (const float*)d_in[17];
    const float* sbhh = (const float*)d_in[18];
    const float* mwih = (const float*)d_in[19];
    const float* mbih = (const float*)d_in[21];
    const float* mbhh = (const float*)d_in[22];
    const float* l1w  = (const float*)d_in[23];
    const float* l1b  = (const float*)d_in[24];
    const float* l3w  = (const float*)d_in[25];
    const float* l3b  = (const float*)d_in[26];

    float* ws   = (float*)d_ws;
    float* dout = (float*)d_out;
    if (ws_size < (size_t)WS_FLOATS * sizeof(float)) return;

    float* agg  = ws + OFF_AGG;
    float* deg  = ws + OFF_DEG;
    float* out  = ws + OFF_OUT;
    float* dinv = ws + OFF_DINV;
    float* At   = ws + OFF_AT;
    float* Bt   = ws + OFF_BT;
    float* bp   = ws + OFF_BP;
    float* ubuf = ws + OFF_U;
    float* vbuf = ws + OFF_V;
    int*   mc   = (int*)(ws + OFF_MC);
    int*   pe   = (int*)(ws + OFF_PE);
    int*   bh   = (int*)(ws + OFF_BH);
    int*   bc   = (int*)(ws + OFF_BC);
    int*   sS   = (int*)(ws + OFF_SS);
    int*   sD   = (int*)(ws + OFF_SD);
    float* sA   = ws + OFF_SA;
    int*   sP   = (int*)(ws + OFF_SP);
    float* pk   = ws + OFF_PK;
    float* gmA  = ws + OFF_GMA;
    float* gsA  = ws + OFF_GSA;
    float* grA  = ws + OFF_GRA;
    float* gmB  = ws + OFF_GMB;
    float* gsB  = ws + OFF_GSB;
    float* grB  = ws + OFF_GRB;
    float* hs   = ws + OFF_HS;
    float* cs   = ws + OFF_CS;
    float* tsa  = ws + OFF_TSA;
    float* tsb  = ws + OFF_TSB;
    float* tma  = ws + OFF_TMA;
    float* tmb  = ws + OFF_TMB;

    hipMemsetAsync(d_ws, 0, (size_t)ZERO_END * sizeof(float), stream);

    k_lin0    <<<(NP*64 + 255)/256, 256, 0, stream>>>(x, l0w, l0b, out);
    k_patterns<<<1, 64, 0, stream>>>(e1w, e1b, bp, ubuf, vbuf, mc);
    k_AB2     <<<65*16, 256, 0, stream>>>(e2w, e2b, ubuf, vbuf, mc, At, Bt);
    k_eprep2  <<<NB_E, 256, 0, stream>>>(ei, ea, bp, mc, deg, pe, bh);
    k_scan2   <<<60, 256, 0, stream>>>(deg, dinv, bh, bc);
    k_scatter2<<<NB_E, 256, 0, stream>>>(ei, ea, pe, bc, sS, sD, sA, sP);
    k_wt2     <<<(7*4096 + 255)/256, 256, 0, stream>>>(rootw, gwhh, gwih, pk);
    k_wt3     <<<(4*16384 + 255)/256, 256, 0, stream>>>(swih, swhh, mwih, tsa, tsb, tma, tmb);

    for (int s = 0; s < 6; ++s) {
        k_edge4<<<EB, 256, 0, stream>>>(sS, sD, sA, sP, out, At, Bt, dinv, agg);
        k_gru9 <<<NP/64, 512, 0, stream>>>(out, agg, pk, convb, gbih, gbhh);
    }

    for (int it = 0; it < 6; ++it) {
        float* gm_rd = (it & 1) ? gmA : gmB;   // unused at it=0
        float* gs_rd = (it & 1) ? gsA : gsB;
        float* gr_rd = (it & 1) ? grA : grB;
        float* gm_wr = (it & 1) ? gmB : gmA;
        float* gs_wr = (it & 1) ? gsB : gsA;
        float* gr_wr = (it & 1) ? grB : grA;
        k_s2s<<<256, 512, 0, stream>>>(tsa, tsb, sbih, sbhh, hs, cs, out,
                                       gm_rd, gs_rd, gr_rd, gm_wr, gs_wr, gr_wr, it);
    }

    // it=5 wrote the B buffers
    k_final2<<<1, 256, 0, stream>>>(tma, tmb, mbih, mbhh, hs, gmB, gsB, grB,
                                    l1w, l1b, l3w, l3b, dout);
}

// Round 12
// 436.214 us; speedup vs baseline: 1.6288x; 1.0389x over previous
//
#include <hip/hip_runtime.h>
#include <math.h>

#define Nn 15000
#define NP 15040   // padded node count (64-node gru tiles, no bounds checks)
#define Ee 30000
#define NB_E 118   // ceil(Ee/256)
#define EB 938     // k_edge4 blocks (3752 waves x 8 edges)

// ---- workspace layout (float offsets) ----
// zero region (zeroed by k_setup each call):
#define OFF_AGG   0          // [NP*64]
#define OFF_DEG   962560     // [Nn]
#define ZERO_END  977560     // 244390 float4s
// written-before-read region:
#define OFF_OUT   977568     // [NP*64]
#define OFF_DINV  1940128    // [Nn]
#define OFF_AT    1955136    // [65*4096] transposed: At[p][o*64+i]
#define OFF_BT    2221376    // [65*4096]
#define OFF_BP    2487616    // [64]
#define OFF_U     2487680    // [65*64]
#define OFF_V     2491840    // [65*64]
#define OFF_MC    2496000    // [1] int
#define OFF_PE    2496016    // [Ee] int
#define OFF_BH    2526016    // [NB_E*65] int
#define OFF_BC    2533696    // [NB_E*65] int
#define OFF_SS    2541376    // [Ee] int
#define OFF_SD    2571376    // [Ee] int
#define OFF_SA    2601376    // [Ee] float
#define OFF_SP    2631376    // [Ee] int
#define OFF_PK    2661376    // [7*4096] packed GRU weights
#define OFF_GMA   2690048    // [256]
#define OFF_GSA   2690304    // [256]
#define OFF_GRA   2690560    // [256*64]
#define OFF_GMB   2706944    // [256]
#define OFF_GSB   2707200    // [256]
#define OFF_GRB   2707456    // [256*64]
#define OFF_HS    2723840    // [64]
#define OFF_CS    2723904    // [64]
// transposed Set2Set / mem LSTM weights (coalesced reads):
#define OFF_TSA   2723968    // [64*256] sa[i*256+g] = swih[g][i]+swhh[g][i]
#define OFF_TSB   2740352    // [64*256] sb[i*256+g] = swih[g][64+i]
#define OFF_TMA   2756736    // [64*256] ma[i*256+g] = mwih[g][i]
#define OFF_TMB   2773120    // [64*256] mb[i*256+g] = mwih[g][64+i]
#define WS_FLOATS 2789504

// k_setup block ranges
#define SB_LIN0   3760       // blocks [0,3760): lin0  (3760*256 == NP*64)
#define SB_PAT    3760       // block 3760: patterns
#define SB_WT2    3761       // blocks [3761,3873): wt2 (112*256 == 7*4096)
#define SB_WT3    3873       // blocks [3873,4129): wt3 (256*256 == 4*16384)
#define SB_ZERO   4129       // blocks [4129,5084): zero region (955 blocks)
#define SB_TOTAL  5084
#define ZERO_F4   244390

__device__ __forceinline__ float sigf(float x) { return 1.0f / (1.0f + expf(-x)); }
__device__ __forceinline__ float bcast(float v, int l) {
    return __int_as_float(__builtin_amdgcn_readlane(__float_as_int(v), l));
}
__device__ __forceinline__ int bcasti(int v, int l) {
    return __builtin_amdgcn_readlane(v, l);
}

// fused setup: lin0 | patterns | wt2 | wt3 | zero(agg,deg) — all independent
__global__ __launch_bounds__(256) void k_setup(
        const float* __restrict__ x, const float* __restrict__ l0w,
        const float* __restrict__ l0b, float* __restrict__ out,
        const float* __restrict__ e1w, const float* __restrict__ e1b,
        float* __restrict__ bp, float* __restrict__ u, float* __restrict__ v,
        int* __restrict__ mc,
        const float* __restrict__ rootw, const float* __restrict__ whh,
        const float* __restrict__ wih, float* __restrict__ pk,
        const float* __restrict__ swih, const float* __restrict__ swhh,
        const float* __restrict__ mwih,
        float* __restrict__ tsa, float* __restrict__ tsb,
        float* __restrict__ tma, float* __restrict__ tmb,
        float* __restrict__ zbase) {
    int b = blockIdx.x, tid = threadIdx.x;
    if (b < SB_LIN0) {
        int idx = b*256 + tid;
        int n = idx >> 6, o = idx & 63;
        float vv = 0.f;
        if (n < Nn)
            vv = fmaxf(l0b[o] + x[n*3+0]*l0w[o*3+0] + x[n*3+1]*l0w[o*3+1]
                       + x[n*3+2]*l0w[o*3+2], 0.f);
        out[idx] = vv;
    } else if (b == SB_PAT) {
        __shared__ float t[64]; __shared__ int valid[64];
        __shared__ float sbp[65]; __shared__ int cnt;
        int k = tid;
        float w1 = 0.f, b1 = 0.f, tv = 0.f; int va = 0;
        if (k < 64) {
            w1 = e1w[k]; b1 = e1b[k];
            if (w1 != 0.f) { tv = -b1 / w1; va = (tv > 0.f && tv < 1.f) ? 1 : 0; }
            t[k] = tv; valid[k] = va;
        }
        __syncthreads();
        if (k < 64 && va) {
            int rank = 0;
            for (int kk = 0; kk < 64; ++kk)
                if (valid[kk] && (t[kk] < tv || (t[kk] == tv && kk < k))) rank++;
            sbp[rank] = tv;
        }
        if (k == 0) { int c = 0; for (int kk = 0; kk < 64; ++kk) c += valid[kk]; cnt = c; *mc = c; }
        __syncthreads();
        if (k < 64) {
            int m = cnt;
            if (k < m) bp[k] = sbp[k];
            for (int j = 0; j <= m; ++j) {
                float lo = (j == 0) ? 0.f : sbp[j-1];
                float hi = (j == m) ? 1.f : sbp[j];
                float c = 0.5f * (lo + hi);
                int msk = (c * w1 + b1) > 0.f;
                u[j*64 + k] = msk ? w1 : 0.f;
                v[j*64 + k] = msk ? b1 : 0.f;
            }
        }
    } else if (b < SB_WT3) {
        int idx = (b - SB_WT2)*256 + tid;   // < 7*4096
        int g = idx >> 12;
        int t2 = idx & 4095;
        int q4 = t2 >> 2, k = t2 & 3;
        int lane = q4 & 63;
        int i4 = q4 >> 6;
        int i = i4*4 + k;
        float vv;
        if (g == 0)      vv = rootw[i*64 + lane];
        else if (g < 4)  vv = whh[((g-1)*64 + lane)*64 + i];
        else             vv = wih[((g-4)*64 + lane)*64 + i];
        pk[idx] = vv;
    } else if (b < SB_ZERO) {
        int idx = (b - SB_WT3)*256 + tid;   // < 4*16384
        int t2 = idx >> 14, r = idx & 16383;
        int i = r >> 8, g = r & 255;
        if (t2 == 0)      tsa[r] = swih[g*128 + i] + swhh[g*64 + i];
        else if (t2 == 1) tsb[r] = swih[g*128 + 64 + i];
        else if (t2 == 2) tma[r] = mwih[g*128 + i];
        else              tmb[r] = mwih[g*128 + 64 + i];
    } else {
        int idx = (b - SB_ZERO)*256 + tid;
        if (idx < ZERO_F4)
            ((float4*)zbase)[idx] = make_float4(0.f, 0.f, 0.f, 0.f);
    }
}

// fused: AB build (blocks [0,1040)) | eprep (blocks [1040,1158))
__global__ __launch_bounds__(256) void k_prep(
        const float* __restrict__ e2w, const float* __restrict__ e2b,
        const float* __restrict__ u, const float* __restrict__ v,
        const int* __restrict__ mc, float* __restrict__ At, float* __restrict__ Bt,
        const int* __restrict__ ei, const float* __restrict__ ea,
        const float* __restrict__ bp, float* __restrict__ deg,
        int* __restrict__ pe, int* __restrict__ bh) {
    int b = blockIdx.x, tid = threadIdx.x;
    if (b < 1040) {
        int j = b >> 4;
        if (j > *mc) return;
        int qc = b & 15;
        __shared__ float su[64], sv[64];
        if (tid < 64) { su[tid] = u[j*64+tid]; sv[tid] = v[j*64+tid]; }
        __syncthreads();
        int q = qc*256 + tid;
        int i = q >> 6, o = q & 63;
        const float* row = e2w + q*64;
        float a = 0.f, bb = 0.f;
        #pragma unroll 8
        for (int k = 0; k < 64; ++k) { float w = row[k]; a = fmaf(su[k], w, a); bb = fmaf(sv[k], w, bb); }
        At[j*4096 + o*64 + i] = a;
        Bt[j*4096 + o*64 + i] = bb + e2b[q];
    } else {
        int eb = b - 1040;
        __shared__ int lh[65];
        if (tid < 65) lh[tid] = 0;
        __syncthreads();
        int e = eb * 256 + tid;
        if (e < Ee) {
            atomicAdd(&deg[ei[Ee + e]], 1.0f);
            float a = ea[e];
            int m = *mc, p = 0;
            for (int j = 0; j < m; ++j) p += (bp[j] <= a) ? 1 : 0;
            pe[e] = p;
            atomicAdd(&lh[p], 1);
        }
        __syncthreads();
        if (tid < 65) bh[eb*65 + tid] = lh[tid];
    }
}

__global__ void k_scan2(const float* __restrict__ deg, float* __restrict__ dinv,
                        const int* __restrict__ bh, int* __restrict__ bc) {
    int tid = threadIdx.x;
    if (blockIdx.x < 59) {
        int n = blockIdx.x * 256 + tid;
        if (n < Nn) dinv[n] = 1.0f / fmaxf(deg[n], 1.0f);
        return;
    }
    __shared__ int stot[65]; __shared__ int sbase[65];
    if (tid < 65) {
        int t = 0;
        for (int b = 0; b < NB_E; ++b) t += bh[b*65 + tid];
        stot[tid] = t;
    }
    __syncthreads();
    if (tid == 0) {
        int run = 0;
        for (int j = 0; j < 65; ++j) { sbase[j] = run; run += stot[j]; }
    }
    __syncthreads();
    if (tid < 65) {
        int run = sbase[tid];
        for (int b = 0; b < NB_E; ++b) { bc[b*65 + tid] = run; run += bh[b*65 + tid]; }
    }
}

__global__ void k_scatter2(const int* __restrict__ ei, const float* __restrict__ ea,
                           const int* __restrict__ pe, const int* __restrict__ bc,
                           int* __restrict__ sS, int* __restrict__ sD,
                           float* __restrict__ sA, int* __restrict__ sP) {
    __shared__ int cur[65];
    int tid = threadIdx.x;
    if (tid < 65) cur[tid] = bc[blockIdx.x*65 + tid];
    __syncthreads();
    int e = blockIdx.x * 256 + tid;
    if (e >= Ee) return;
    int p = pe[e];
    int pos = atomicAdd(&cur[p], 1);
    sS[pos] = ei[e]; sD[pos] = ei[Ee + e]; sA[pos] = ea[e]; sP[pos] = p;
}

// pattern-sorted edges; chunk metadata lane-parallel; h-row pipelined one ahead.
__global__ __launch_bounds__(256) void k_edge4(
        const int* __restrict__ sS, const int* __restrict__ sD,
        const float* __restrict__ sA, const int* __restrict__ sP,
        const float* __restrict__ out, const float* __restrict__ At,
        const float* __restrict__ Bt, const float* __restrict__ dinv,
        float* __restrict__ agg) {
    int tid = threadIdx.x, lane = tid & 63;
    int wid = (blockIdx.x * 256 + tid) >> 6;
    const int CH = 8;
    int e0 = wid * CH;
    if (e0 >= Ee) return;
    int e1 = e0 + CH; if (e1 > Ee) e1 = Ee;
    int cnt = e1 - e0;

    int eidx = e0 + lane;
    int msrc = 0, mdst = 0, mp = 0; float ma = 0.f, mdv = 0.f;
    if (lane < cnt) {
        msrc = sS[eidx]; mdst = sD[eidx]; ma = sA[eidx]; mp = sP[eidx];
        mdv = dinv[mdst];
    }

    float Ar[64], Br[64];
    int curp = -1;
    float hv_next = out[bcasti(msrc, 0)*64 + lane];
    for (int j = 0; j < cnt; ++j) {
        float hv = hv_next;
        if (j+1 < cnt) hv_next = out[bcasti(msrc, j+1)*64 + lane];
        int p = bcasti(mp, j);
        if (p != curp) {
            curp = p;
            const float4* Ap4 = (const float4*)(At + p*4096 + lane*64);
            const float4* Bp4 = (const float4*)(Bt + p*4096 + lane*64);
            #pragma unroll
            for (int q = 0; q < 16; ++q) {
                float4 av = Ap4[q], bv = Bp4[q];
                Ar[q*4+0]=av.x; Ar[q*4+1]=av.y; Ar[q*4+2]=av.z; Ar[q*4+3]=av.w;
                Br[q*4+0]=bv.x; Br[q*4+1]=bv.y; Br[q*4+2]=bv.z; Br[q*4+3]=bv.w;
            }
        }
        float a = bcast(ma, j);
        float acc0 = 0.f, acc1 = 0.f;
        #pragma unroll
        for (int i = 0; i < 64; i += 2) {
            float h0 = bcast(hv, i);
            float h1 = bcast(hv, i+1);
            acc0 = fmaf(h0, fmaf(a, Ar[i],   Br[i]),   acc0);
            acc1 = fmaf(h1, fmaf(a, Ar[i+1], Br[i+1]), acc1);
        }
        float acc = (acc0 + acc1) * bcast(mdv, j);
        atomicAdd(&agg[bcasti(mdst, j)*64 + lane], acc);
    }
}

// fused NNConv-root + GRU: weights in LDS (112KB), wave owns 8 nodes end-to-end.
__global__ __launch_bounds__(512, 2) void k_gru9(
        float* __restrict__ out, float* __restrict__ agg,
        const float* __restrict__ pk, const float* __restrict__ convb,
        const float* __restrict__ gbih, const float* __restrict__ gbhh) {
    __shared__ __align__(16) float wL[7*4096];   // 112 KB
    int tid = threadIdx.x, lane = tid & 63, w = tid >> 6;
    {
        const float4* src = (const float4*)pk;
        float4* dst = (float4*)wL;
        #pragma unroll
        for (int i = 0; i < 14; ++i) dst[i*512 + tid] = src[i*512 + tid];
    }
    __syncthreads();
    const float4* wL4 = (const float4*)wL;
    int n0 = blockIdx.x*64 + w*8;

    float hv[8], mv[8], ghr[8], ghz[8], ghn[8];
    #pragma unroll
    for (int k = 0; k < 8; ++k) hv[k] = out[(n0+k)*64 + lane];

    float a0[8], a1[8], a2[8], a3[8];
    #pragma unroll
    for (int k = 0; k < 8; ++k) { a0[k]=0.f; a1[k]=0.f; a2[k]=0.f; a3[k]=0.f; }
    #pragma unroll 4
    for (int i4 = 0; i4 < 16; ++i4) {
        float4 w0 = wL4[(0*16+i4)*64 + lane];
        float4 w1 = wL4[(1*16+i4)*64 + lane];
        float4 w2 = wL4[(2*16+i4)*64 + lane];
        float4 w3 = wL4[(3*16+i4)*64 + lane];
        #pragma unroll
        for (int k = 0; k < 8; ++k) {
            float h;
            h = bcast(hv[k], i4*4+0);
            a0[k]=fmaf(h,w0.x,a0[k]); a1[k]=fmaf(h,w1.x,a1[k]);
            a2[k]=fmaf(h,w2.x,a2[k]); a3[k]=fmaf(h,w3.x,a3[k]);
            h = bcast(hv[k], i4*4+1);
            a0[k]=fmaf(h,w0.y,a0[k]); a1[k]=fmaf(h,w1.y,a1[k]);
            a2[k]=fmaf(h,w2.y,a2[k]); a3[k]=fmaf(h,w3.y,a3[k]);
            h = bcast(hv[k], i4*4+2);
            a0[k]=fmaf(h,w0.z,a0[k]); a1[k]=fmaf(h,w1.z,a1[k]);
            a2[k]=fmaf(h,w2.z,a2[k]); a3[k]=fmaf(h,w3.z,a3[k]);
            h = bcast(hv[k], i4*4+3);
            a0[k]=fmaf(h,w0.w,a0[k]); a1[k]=fmaf(h,w1.w,a1[k]);
            a2[k]=fmaf(h,w2.w,a2[k]); a3[k]=fmaf(h,w3.w,a3[k]);
        }
    }
    float cbv = convb[lane];
    #pragma unroll
    for (int k = 0; k < 8; ++k) {
        int gi = (n0+k)*64 + lane;
        float av = agg[gi]; agg[gi] = 0.f;
        mv[k] = fmaxf(a0[k] + av + cbv, 0.f);
        ghr[k] = a1[k]; ghz[k] = a2[k]; ghn[k] = a3[k];
    }

    #pragma unroll
    for (int k = 0; k < 8; ++k) { a0[k]=0.f; a1[k]=0.f; a2[k]=0.f; }
    #pragma unroll 4
    for (int i4 = 0; i4 < 16; ++i4) {
        float4 w4v = wL4[(4*16+i4)*64 + lane];
        float4 w5v = wL4[(5*16+i4)*64 + lane];
        float4 w6v = wL4[(6*16+i4)*64 + lane];
        #pragma unroll
        for (int k = 0; k < 8; ++k) {
            float h;
            h = bcast(mv[k], i4*4+0);
            a0[k]=fmaf(h,w4v.x,a0[k]); a1[k]=fmaf(h,w5v.x,a1[k]); a2[k]=fmaf(h,w6v.x,a2[k]);
            h = bcast(mv[k], i4*4+1);
            a0[k]=fmaf(h,w4v.y,a0[k]); a1[k]=fmaf(h,w5v.y,a1[k]); a2[k]=fmaf(h,w6v.y,a2[k]);
            h = bcast(mv[k], i4*4+2);
            a0[k]=fmaf(h,w4v.z,a0[k]); a1[k]=fmaf(h,w5v.z,a1[k]); a2[k]=fmaf(h,w6v.z,a2[k]);
            h = bcast(mv[k], i4*4+3);
            a0[k]=fmaf(h,w4v.w,a0[k]); a1[k]=fmaf(h,w5v.w,a1[k]); a2[k]=fmaf(h,w6v.w,a2[k]);
        }
    }

    float br  = gbih[lane]      + gbhh[lane];
    float bz  = gbih[64+lane]   + gbhh[64+lane];
    float bnI = gbih[128+lane];
    float bnH = gbhh[128+lane];
    #pragma unroll
    for (int k = 0; k < 8; ++k) {
        float r  = sigf(a0[k] + ghr[k] + br);
        float z  = sigf(a1[k] + ghz[k] + bz);
        float nn = tanhf(fmaf(r, ghn[k] + bnH, a2[k] + bnI));
        out[(n0+k)*64 + lane] = (1.f - z)*nn + z*hv[k];
    }
}

// Set2Set iteration: wave-reduce finalize (2 barriers) + coalesced LSTM + partials.
__global__ __launch_bounds__(512) void k_s2s(
        const float* __restrict__ tsa, const float* __restrict__ tsb,
        const float* __restrict__ bih, const float* __restrict__ bhh,
        float* __restrict__ hs, float* __restrict__ cs,
        const float* __restrict__ out,
        const float* __restrict__ gmax_rd, const float* __restrict__ gsum_rd,
        const float* __restrict__ gr_rd,
        float* __restrict__ gmax_wr, float* __restrict__ gsum_wr,
        float* __restrict__ gr_wr, int it) {
    __shared__ float red[512], shs[64], scs[64], srv[64], sg[256];
    __shared__ float wred[8], zred[8];
    __shared__ float sm_m[8], sm_z[8], sm_r[8][64];
    int tid = threadIdx.x, lane = tid & 63, w = tid >> 6;
    if (it == 0) {
        if (tid < 64) { shs[tid] = 0.f; scs[tid] = 0.f; srv[tid] = 0.f; }
        __syncthreads();
    } else {
        float gm = (tid < 256) ? gmax_rd[tid] : -3.4e38f;
        float wm = gm;
        #pragma unroll
        for (int off = 32; off > 0; off >>= 1) wm = fmaxf(wm, __shfl_xor(wm, off, 64));
        if (lane == 0) wred[w] = wm;
        __syncthreads();
        float M = fmaxf(fmaxf(fmaxf(wred[0], wred[1]), fmaxf(wred[2], wred[3])),
                        fmaxf(fmaxf(wred[4], wred[5]), fmaxf(wred[6], wred[7])));
        float zt = (tid < 256) ? gsum_rd[tid] * expf(gm - M) : 0.f;
        #pragma unroll
        for (int off = 32; off > 0; off >>= 1) zt += __shfl_xor(zt, off, 64);
        if (lane == 0) zred[w] = zt;
        float racc = 0.f;
        for (int b2 = w; b2 < 256; b2 += 8)
            racc = fmaf(gr_rd[b2*64 + lane], expf(gmax_rd[b2] - M), racc);
        red[tid] = racc;
        if (tid < 64) { shs[tid] = hs[tid]; scs[tid] = cs[tid]; }
        __syncthreads();
        if (w == 0) {
            float Z = zred[0]+zred[1]+zred[2]+zred[3]+zred[4]+zred[5]+zred[6]+zred[7];
            float s = 0.f;
            #pragma unroll
            for (int k = 0; k < 8; ++k) s += red[k*64 + lane];
            srv[lane] = s / Z;
        }
        __syncthreads();
    }
    // LSTM gates via transposed tables: coalesced loads
    if (tid < 256) {
        float g = bih[tid] + bhh[tid];
        #pragma unroll 8
        for (int i = 0; i < 64; ++i)
            g += shs[i]*tsa[i*256 + tid] + srv[i]*tsb[i*256 + tid];
        sg[tid] = g;
    }
    __syncthreads();
    if (tid < 64) {
        float ii = sigf(sg[tid]), ff = sigf(sg[64+tid]);
        float gg = tanhf(sg[128+tid]), oo = sigf(sg[192+tid]);
        float c2 = ff*scs[tid] + ii*gg;
        float hn = oo*tanhf(c2);
        shs[tid] = hn;
        if (blockIdx.x == 0) { hs[tid] = hn; cs[tid] = c2; }
    }
    __syncthreads();
    float hsv = shs[lane];
    float m = -3.4e38f, Z2 = 0.f, racc2 = 0.f;
    for (int n = blockIdx.x*8 + w; n < Nn; n += 2048) {
        float ov = out[n*64 + lane];
        float p = ov * hsv;
        #pragma unroll
        for (int off = 32; off > 0; off >>= 1) p += __shfl_xor(p, off, 64);
        float mn = fmaxf(m, p);
        float sc = expf(m - mn);
        float t  = expf(p - mn);
        Z2 = fmaf(Z2, sc, t);
        racc2 = fmaf(racc2, sc, t*ov);
        m = mn;
    }
    if (lane == 0) { sm_m[w] = m; sm_z[w] = Z2; }
    sm_r[w][lane] = racc2;
    __syncthreads();
    if (w == 0) {
        float M = sm_m[0];
        #pragma unroll
        for (int j = 1; j < 8; ++j) M = fmaxf(M, sm_m[j]);
        float Zb = 0.f, rb = 0.f;
        #pragma unroll
        for (int j = 0; j < 8; ++j) {
            float e = expf(sm_m[j] - M);
            Zb = fmaf(sm_z[j], e, Zb);
            rb = fmaf(sm_r[j][lane], e, rb);
        }
        gr_wr[blockIdx.x*64 + lane] = rb;
        if (lane == 0) { gmax_wr[blockIdx.x] = M; gsum_wr[blockIdx.x] = Zb; }
    }
}

// final: wave-reduce finalize, mem-LSTM (h=c=0, transposed weights), lin1, lin3
__global__ __launch_bounds__(256) void k_final2(
        const float* __restrict__ tma, const float* __restrict__ tmb,
        const float* __restrict__ mbih, const float* __restrict__ mbhh,
        const float* __restrict__ hs,
        const float* __restrict__ gmax, const float* __restrict__ gsum,
        const float* __restrict__ gr,
        const float* __restrict__ l1w, const float* __restrict__ l1b,
        const float* __restrict__ l3w, const float* __restrict__ l3b,
        float* __restrict__ dout) {
    __shared__ float red[256], shs[64], srv[64], sg[256], shx[64], so[64];
    __shared__ float wred[4], zred[4];
    int tid = threadIdx.x, lane = tid & 63, w = tid >> 6;
    {
        float gm = gmax[tid];
        float wm = gm;
        #pragma unroll
        for (int off = 32; off > 0; off >>= 1) wm = fmaxf(wm, __shfl_xor(wm, off, 64));
        if (lane == 0) wred[w] = wm;
        __syncthreads();
        float M = fmaxf(fmaxf(wred[0], wred[1]), fmaxf(wred[2], wred[3]));
        float zt = gsum[tid] * expf(gm - M);
        #pragma unroll
        for (int off = 32; off > 0; off >>= 1) zt += __shfl_xor(zt, off, 64);
        if (lane == 0) zred[w] = zt;
        float racc = 0.f;
        for (int b2 = w; b2 < 256; b2 += 4)
            racc = fmaf(gr[b2*64 + lane], expf(gmax[b2] - M), racc);
        red[tid] = racc;
        if (tid < 64) shs[tid] = hs[tid];
        __syncthreads();
        if (w == 0) {
            float Z = zred[0]+zred[1]+zred[2]+zred[3];
            srv[lane] = (red[lane] + red[64+lane] + red[128+lane] + red[192+lane]) / Z;
        }
    }
    __syncthreads();
    {
        float g = mbih[tid] + mbhh[tid];
        #pragma unroll 8
        for (int i = 0; i < 64; ++i)
            g += shs[i]*tma[i*256 + tid] + srv[i]*tmb[i*256 + tid];
        sg[tid] = g;
    }
    __syncthreads();
    if (tid < 64) {
        float ii = sigf(sg[tid]);
        float gg = tanhf(sg[128+tid]);
        float oo = sigf(sg[192+tid]);
        float c2 = ii * gg;
        float hx = oo * tanhf(c2);
        shx[tid] = hx;
        dout[1 + tid] = hx;
        dout[65 + tid] = c2;
    }
    __syncthreads();
    if (tid < 64) {
        float a = l1b[tid];
        const float* wr = l1w + tid*64;
        #pragma unroll 8
        for (int i = 0; i < 64; ++i) a = fmaf(shx[i], wr[i], a);
        so[tid] = fmaxf(a, 0.f);
    }
    __syncthreads();
    if (tid == 0) {
        float v = l3b[0];
        for (int i = 0; i < 64; ++i) v = fmaf(so[i], l3w[i], v);
        dout[0] = v;
    }
}

extern "C" void kernel_launch(void* const* d_in, const int* in_sizes, int n_in,
                              void* d_out, int out_size, void* d_ws, size_t ws_size,
                              hipStream_t stream) {
    const float* x    = (const float*)d_in[0];
    const int*   ei   = (const int*)  d_in[1];
    const float* ea   = (const float*)d_in[2];
    const float* l0w  = (const float*)d_in[3];
    const float* l0b  = (const float*)d_in[4];
    const float* e1w  = (const float*)d_in[5];
    const float* e1b  = (const float*)d_in[6];
    const float* e2w  = (const float*)d_in[7];
    const float* e2b  = (const float*)d_in[8];
    const float* rootw= (const float*)d_in[9];
    const float* convb= (const float*)d_in[10];
    const float* gwih = (const float*)d_in[11];
    const float* gwhh = (const float*)d_in[12];
    const float* gbih = (const float*)d_in[13];
    const float* gbhh = (const float*)d_in[14];
    const float* swih = (const float*)d_in[15];
    const float* swhh = (const float*)d_in[16];
    const float* sbih = (const float*)d_in[17];
    const float* sbhh = (const float*)d_in[18];
    const float* mwih = (const float*)d_in[19];
    const float* mbih = (const float*)d_in[21];
    const float* mbhh = (const float*)d_in[22];
    const float* l1w  = (const float*)d_in[23];
    const float* l1b  = (const float*)d_in[24];
    const float* l3w  = (const float*)d_in[25];
    const float* l3b  = (const float*)d_in[26];

    float* ws   = (float*)d_ws;
    float* dout = (float*)d_out;
    if (ws_size < (size_t)WS_FLOATS * sizeof(float)) return;

    float* agg  = ws + OFF_AGG;
    float* deg  = ws + OFF_DEG;
    float* out  = ws + OFF_OUT;
    float* dinv = ws + OFF_DINV;
    float* At   = ws + OFF_AT;
    float* Bt   = ws + OFF_BT;
    float* bp   = ws + OFF_BP;
    float* ubuf = ws + OFF_U;
    float* vbuf = ws + OFF_V;
    int*   mc   = (int*)(ws + OFF_MC);
    int*   pe   = (int*)(ws + OFF_PE);
    int*   bh   = (int*)(ws + OFF_BH);
    int*   bc   = (int*)(ws + OFF_BC);
    int*   sS   = (int*)(ws + OFF_SS);
    int*   sD   = (int*)(ws + OFF_SD);
    float* sA   = ws + OFF_SA;
    int*   sP   = (int*)(ws + OFF_SP);
    float* pk   = ws + OFF_PK;
    float* gmA  = ws + OFF_GMA;
    float* gsA  = ws + OFF_GSA;
    float* grA  = ws + OFF_GRA;
    float* gmB  = ws + OFF_GMB;
    float* gsB  = ws + OFF_GSB;
    float* grB  = ws + OFF_GRB;
    float* hs   = ws + OFF_HS;
    float* cs   = ws + OFF_CS;
    float* tsa  = ws + OFF_TSA;
    float* tsb  = ws + OFF_TSB;
    float* tma  = ws + OFF_TMA;
    float* tmb  = ws + OFF_TMB;

    k_setup   <<<SB_TOTAL, 256, 0, stream>>>(x, l0w, l0b, out, e1w, e1b, bp, ubuf,
                                             vbuf, mc, rootw, gwhh, gwih, pk,
                                             swih, swhh, mwih, tsa, tsb, tma, tmb,
                                             ws + OFF_AGG);
    k_prep    <<<1040 + NB_E, 256, 0, stream>>>(e2w, e2b, ubuf, vbuf, mc, At, Bt,
                                                ei, ea, bp, deg, pe, bh);
    k_scan2   <<<60, 256, 0, stream>>>(deg, dinv, bh, bc);
    k_scatter2<<<NB_E, 256, 0, stream>>>(ei, ea, pe, bc, sS, sD, sA, sP);

    for (int s = 0; s < 6; ++s) {
        k_edge4<<<EB, 256, 0, stream>>>(sS, sD, sA, sP, out, At, Bt, dinv, agg);
        k_gru9 <<<NP/64, 512, 0, stream>>>(out, agg, pk, convb, gbih, gbhh);
    }

    for (int it = 0; it < 6; ++it) {
        float* gm_rd = (it & 1) ? gmA : gmB;   // unused at it=0
        float* gs_rd = (it & 1) ? gsA : gsB;
        float* gr_rd = (it & 1) ? grA : grB;
        float* gm_wr = (it & 1) ? gmB : gmA;
        float* gs_wr = (it & 1) ? gsB : gsA;
        float* gr_wr = (it & 1) ? grB : grA;
        k_s2s<<<256, 512, 0, stream>>>(tsa, tsb, sbih, sbhh, hs, cs, out,
                                       gm_rd, gs_rd, gr_rd, gm_wr, gs_wr, gr_wr, it);
    }

    // it=5 wrote the B buffers
    k_final2<<<1, 256, 0, stream>>>(tma, tmb, mbih, mbhh, hs, gmB, gsB, grB,
                                    l1w, l1b, l3w, l3b, dout);
}